// Round 1
// baseline (10739.249 us; speedup 1.0000x reference)
//
#include <hip/hip_runtime.h>

typedef __attribute__((ext_vector_type(8))) short short8;
typedef __attribute__((ext_vector_type(4))) float f32x4;

#define DEVINL __device__ __forceinline__

DEVINL unsigned short f2bf(float f) {
  unsigned int u = __builtin_bit_cast(unsigned int, f);
  unsigned int r = u + 0x7FFFu + ((u >> 16) & 1u);  // RNE
  return (unsigned short)(r >> 16);
}
DEVINL float sig_(float x) { return 1.f / (1.f + __expf(-x)); }
DEVINL float tanh_(float x) { return 2.f / (1.f + __expf(-2.f * x)) - 1.f; }

DEVINL void gld16(void* lds, const void* g) {
  __builtin_amdgcn_global_load_lds(
      (const __attribute__((address_space(1))) unsigned int*)g,
      (__attribute__((address_space(3))) unsigned int*)lds, 16, 0, 0);
}

// ---------------------------------------------------------------------------
// bf16 GEMM: C[M,N] = A[M,K] @ Bt[N,K]^T + bias[N]
// 128x128 tile, BK=32, 4 waves (2x2 of 64x64), 16x16x32 bf16 MFMA.
// mode 0: C[m*N+n] (guard m<Mvalid). mode 1: logits scatter m=(t*32+b) ->
//         C[b*63*32000 + t*32000 + n], guard m<Mvalid.
// ---------------------------------------------------------------------------
__global__ __launch_bounds__(256) void gemm_bf16(
    const unsigned short* __restrict__ A, const unsigned short* __restrict__ Bt,
    float* __restrict__ C, const float* __restrict__ bias,
    int K, int N, int Mvalid, int mode) {
  __shared__ unsigned short lA[512 * 8];
  __shared__ unsigned short lB[512 * 8];
  const int tid = threadIdx.x;
  const int lane = tid & 63, wid = tid >> 6;
  const int wm = wid >> 1, wn = wid & 1;
  const int bn = blockIdx.x, bm = blockIdx.y;
  const size_t K_ = (size_t)K;

  // staging slots: slot = kb*128 + row  (kb = k-chunk of 8, row = tile row)
  const int s0 = tid, s1 = tid + 256;
  const int r0 = s0 & 127, kb0 = s0 >> 7;
  const int r1 = s1 & 127, kb1 = s1 >> 7;
  const unsigned short* gA0 = A + (size_t)(bm * 128 + r0) * K_ + kb0 * 8;
  const unsigned short* gA1 = A + (size_t)(bm * 128 + r1) * K_ + kb1 * 8;
  const unsigned short* gB0 = Bt + (size_t)(bn * 128 + r0) * K_ + kb0 * 8;
  const unsigned short* gB1 = Bt + (size_t)(bn * 128 + r1) * K_ + kb1 * 8;
  unsigned short* lA0 = lA + (size_t)(wid * 64) * 8;
  unsigned short* lA1 = lA + (size_t)(256 + wid * 64) * 8;
  unsigned short* lB0 = lB + (size_t)(wid * 64) * 8;
  unsigned short* lB1 = lB + (size_t)(256 + wid * 64) * 8;

  f32x4 acc[4][4] = {};
  const int kg = lane >> 4, lr = lane & 15;

  for (int kt = 0; kt < K; kt += 32) {
    gld16(lA0, gA0 + kt);
    gld16(lA1, gA1 + kt);
    gld16(lB0, gB0 + kt);
    gld16(lB1, gB1 + kt);
    __syncthreads();
    short8 af[4], bfr[4];
#pragma unroll
    for (int fm = 0; fm < 4; fm++)
      af[fm] = *(const short8*)&lA[(size_t)(kg * 128 + wm * 64 + fm * 16 + lr) * 8];
#pragma unroll
    for (int fn = 0; fn < 4; fn++)
      bfr[fn] = *(const short8*)&lB[(size_t)(kg * 128 + wn * 64 + fn * 16 + lr) * 8];
#pragma unroll
    for (int fm = 0; fm < 4; fm++)
#pragma unroll
      for (int fn = 0; fn < 4; fn++)
        acc[fm][fn] =
            __builtin_amdgcn_mfma_f32_16x16x32_bf16(af[fm], bfr[fn], acc[fm][fn], 0, 0, 0);
    __syncthreads();
  }

#pragma unroll
  for (int fn = 0; fn < 4; fn++) {
    const int col = bn * 128 + wn * 64 + fn * 16 + lr;
    const float bv = bias ? bias[col] : 0.f;
#pragma unroll
    for (int fm = 0; fm < 4; fm++) {
      const int row0 = bm * 128 + wm * 64 + fm * 16 + kg * 4;
#pragma unroll
      for (int r = 0; r < 4; r++) {
        const int m = row0 + r;
        if (m < Mvalid) {
          const float v = acc[fm][fn][r] + bv;
          if (mode == 0) {
            C[(size_t)m * N + col] = v;
          } else {
            const int b = m & 31, t = m >> 5;
            C[(size_t)b * 2016000 + (size_t)t * 32000 + col] = v;
          }
        }
      }
    }
  }
}

// ---------------------------------------------------------------------------
// Recurrence helpers (fp32 exact)
// ---------------------------------------------------------------------------
DEVINL void stage_h(float* lh, const float* hp, int rowStride, int kc) {
  // 32 rows x 256 cols into lh[32][260]; blockDim.x == 128
#pragma unroll 8
  for (int it = 0; it < 64; it++) {
    int idx = threadIdx.x + it * 128;
    int bb = idx >> 8, kk = idx & 255;
    lh[bb * 260 + kk] = hp[(size_t)bb * rowStride + kc * 256 + kk];
  }
}

DEVINL void dot4x(const float* __restrict__ Wi, const float* __restrict__ Wf,
                  const float* __restrict__ Wg, const float* __restrict__ Wo,
                  const float* __restrict__ hh,
                  float& s0, float& s1, float& s2, float& s3) {
#pragma unroll 8
  for (int k = 0; k < 256; k += 4) {
    f32x4 hv = *(const f32x4*)&hh[k];
    f32x4 a = *(const f32x4*)&Wi[k];
    f32x4 b = *(const f32x4*)&Wf[k];
    f32x4 c = *(const f32x4*)&Wg[k];
    f32x4 d = *(const f32x4*)&Wo[k];
    s0 += a.x * hv.x + a.y * hv.y + a.z * hv.z + a.w * hv.w;
    s1 += b.x * hv.x + b.y * hv.y + b.z * hv.z + b.w * hv.w;
    s2 += c.x * hv.x + c.y * hv.y + c.z * hv.z + c.w * hv.w;
    s3 += d.x * hv.x + d.y * hv.y + d.z * hv.z + d.w * hv.w;
  }
}

// Encoder step: grid = 256 (dir*128 + jc), block = 128 (4 j x 32 b)
// h: [2par][2dir][32][512], c: [2dir][32][512]
__global__ __launch_bounds__(128) void enc_step(
    const float* __restrict__ G, const float* __restrict__ Whh,
    float* __restrict__ h, float* __restrict__ c,
    unsigned short* __restrict__ seq_out, int t) {
  const int dir = blockIdx.x >> 7;
  const int j = (blockIdx.x & 127) * 4 + (threadIdx.x >> 5);
  const int b = threadIdx.x & 31;
  const int p = t & 1;
  const int s_idx = dir ? (63 - t) : t;
  const float* hp = h + ((size_t)p * 2 + dir) * (32 * 512);
  __shared__ float lh[32 * 260];
  float s0 = 0, s1 = 0, s2 = 0, s3 = 0;
  const size_t wbase = (size_t)dir * 2048 * 512;
  for (int kc = 0; kc < 2; kc++) {
    __syncthreads();
    stage_h(lh, hp, 512, kc);
    __syncthreads();
    dot4x(Whh + wbase + (size_t)j * 512 + kc * 256,
          Whh + wbase + (size_t)(512 + j) * 512 + kc * 256,
          Whh + wbase + (size_t)(1024 + j) * 512 + kc * 256,
          Whh + wbase + (size_t)(1536 + j) * 512 + kc * 256,
          &lh[b * 260], s0, s1, s2, s3);
  }
  const float* Gr = G + (size_t)(s_idx * 32 + b) * 4096 + dir * 2048;
  const float gi = Gr[j] + s0;
  const float gf = Gr[512 + j] + s1;
  const float gg = Gr[1024 + j] + s2;
  const float go = Gr[1536 + j] + s3;
  const size_t cidx = ((size_t)dir * 32 + b) * 512 + j;
  const float cn = sig_(gf) * c[cidx] + sig_(gi) * tanh_(gg);
  const float hn = sig_(go) * tanh_(cn);
  c[cidx] = cn;
  h[(((size_t)(p ^ 1) * 2 + dir) * 32 + b) * 512 + j] = hn;
  if (seq_out) seq_out[(size_t)(s_idx * 32 + b) * 1024 + dir * 512 + j] = f2bf(hn);
}

// Decoder cell0: grid = 256 (jc), block = 128 (4 j x 32 b). h0: [2par][32][1024]
__global__ __launch_bounds__(128) void dec_step0(
    const float* __restrict__ G0, const float* __restrict__ Whh0,
    float* __restrict__ h0, float* __restrict__ c0, int t) {
  const int j = blockIdx.x * 4 + (threadIdx.x >> 5);
  const int b = threadIdx.x & 31;
  const int p = t & 1;
  const float* hp = h0 + (size_t)p * (32 * 1024);
  __shared__ float lh[32 * 260];
  float s0 = 0, s1 = 0, s2 = 0, s3 = 0;
  for (int kc = 0; kc < 4; kc++) {
    __syncthreads();
    stage_h(lh, hp, 1024, kc);
    __syncthreads();
    dot4x(Whh0 + (size_t)j * 1024 + kc * 256,
          Whh0 + (size_t)(1024 + j) * 1024 + kc * 256,
          Whh0 + (size_t)(2048 + j) * 1024 + kc * 256,
          Whh0 + (size_t)(3072 + j) * 1024 + kc * 256,
          &lh[b * 260], s0, s1, s2, s3);
  }
  const float* Gr = G0 + (size_t)(t * 32 + b) * 4096;
  const float gi = Gr[j] + s0;
  const float gf = Gr[1024 + j] + s1;
  const float gg = Gr[2048 + j] + s2;
  const float go = Gr[3072 + j] + s3;
  const size_t cidx = (size_t)b * 1024 + j;
  const float cn = sig_(gf) * c0[cidx] + sig_(gi) * tanh_(gg);
  const float hn = sig_(go) * tanh_(cn);
  c0[cidx] = cn;
  h0[((size_t)(p ^ 1) * 32 + b) * 1024 + j] = hn;
}

// Decoder cell1 (+ h1 capture for logits GEMM)
__global__ __launch_bounds__(128) void dec_step1(
    const float* __restrict__ Wih1, const float* __restrict__ Whh1,
    const float* __restrict__ db1, const float* __restrict__ h0,
    float* __restrict__ h1, float* __restrict__ c1,
    unsigned short* __restrict__ H1all, int t) {
  const int j = blockIdx.x * 4 + (threadIdx.x >> 5);
  const int b = threadIdx.x & 31;
  const int p = t & 1;
  const float* h0n = h0 + (size_t)(p ^ 1) * (32 * 1024);  // freshly written h0
  const float* h1p = h1 + (size_t)p * (32 * 1024);
  __shared__ float lh[32 * 260];
  float s0 = 0, s1 = 0, s2 = 0, s3 = 0;
  for (int ph = 0; ph < 2; ph++) {
    const float* sp = ph ? h1p : h0n;
    const float* W = ph ? Whh1 : Wih1;
    for (int kc = 0; kc < 4; kc++) {
      __syncthreads();
      stage_h(lh, sp, 1024, kc);
      __syncthreads();
      dot4x(W + (size_t)j * 1024 + kc * 256,
            W + (size_t)(1024 + j) * 1024 + kc * 256,
            W + (size_t)(2048 + j) * 1024 + kc * 256,
            W + (size_t)(3072 + j) * 1024 + kc * 256,
            &lh[b * 260], s0, s1, s2, s3);
    }
  }
  const float gi = db1[j] + s0;
  const float gf = db1[1024 + j] + s1;
  const float gg = db1[2048 + j] + s2;
  const float go = db1[3072 + j] + s3;
  const size_t cidx = (size_t)b * 1024 + j;
  const float cn = sig_(gf) * c1[cidx] + sig_(gi) * tanh_(gg);
  const float hn = sig_(go) * tanh_(cn);
  c1[cidx] = cn;
  h1[((size_t)(p ^ 1) * 32 + b) * 1024 + j] = hn;
  H1all[(size_t)(t * 32 + b) * 1024 + j] = f2bf(hn);
}

// ---------------------------------------------------------------------------
// Setup kernels
// ---------------------------------------------------------------------------
__global__ void cvt_bf16(const float* __restrict__ in, unsigned short* __restrict__ out,
                         long n4) {
  long i = (long)blockIdx.x * blockDim.x + threadIdx.x;
  const long stride = (long)gridDim.x * blockDim.x;
  for (; i < n4; i += stride) {
    f32x4 v = *(const f32x4*)&in[i * 4];
    ushort4 o = {f2bf(v.x), f2bf(v.y), f2bf(v.z), f2bf(v.w)};
    *(ushort4*)&out[i * 4] = o;
  }
}

__global__ void bias_comb(const float* __restrict__ a, const float* __restrict__ b,
                          float* __restrict__ out, int n) {
  int i = blockIdx.x * blockDim.x + threadIdx.x;
  if (i < n) out[i] = a[i] + b[i];
}

// A0[s*32+b][e] = bf16(src_emb[x[b][63-s]][e]); grid 2048, block 256
__global__ void embed_src(const int* __restrict__ x, const float* __restrict__ emb,
                          unsigned short* __restrict__ A0) {
  const int row = blockIdx.x;
  const int s = row >> 5, b = row & 31;
  const int tok = x[b * 64 + (63 - s)];
  const int col = threadIdx.x * 4;
  f32x4 v = *(const f32x4*)(emb + (size_t)tok * 1024 + col);
  ushort4 o = {f2bf(v.x), f2bf(v.y), f2bf(v.z), f2bf(v.w)};
  *(ushort4*)&A0[(size_t)row * 1024 + col] = o;
}

// inp0[t*32+b][0:1024] = bf16(tgt_emb[y[b][t]]); pad rows (>=2016) fully zeroed
__global__ void embed_tgt(const int* __restrict__ y, const float* __restrict__ emb,
                          unsigned short* __restrict__ inp0) {
  const int row = blockIdx.x;
  const int col = threadIdx.x * 4;
  ushort4 o = {0, 0, 0, 0};
  if (row < 2016) {
    const int t = row >> 5, b = row & 31;
    const int tok = y[b * 64 + t];
    f32x4 v = *(const f32x4*)(emb + (size_t)tok * 1024 + col);
    o = ushort4{f2bf(v.x), f2bf(v.y), f2bf(v.z), f2bf(v.w)};
  } else {
    *(ushort4*)&inp0[(size_t)row * 2048 + 1024 + col] = o;  // zero ctx half of pad rows
  }
  *(ushort4*)&inp0[(size_t)row * 2048 + col] = o;
}

// context half of inp0 from encoder layer-1 final h (parity 0); grid 2016
__global__ void fill_ctx(const float* __restrict__ ench1, unsigned short* __restrict__ inp0) {
  const int row = blockIdx.x;
  const int b = row & 31;
  const int col = threadIdx.x * 4;  // 0..1023
  const int dir = col >> 9, jj = col & 511;
  f32x4 v = *(const f32x4*)(ench1 + ((size_t)dir * 32 + b) * 512 + jj);
  ushort4 o = {f2bf(v.x), f2bf(v.y), f2bf(v.z), f2bf(v.w)};
  *(ushort4*)&inp0[(size_t)row * 2048 + 1024 + col] = o;
}

// decoder state init from encoder finals; grid 128 x 256
__global__ void dec_init(const float* __restrict__ ench, const float* __restrict__ encc,
                         float* __restrict__ h0, float* __restrict__ c0,
                         float* __restrict__ h1, float* __restrict__ c1) {
  const int i = blockIdx.x * 256 + threadIdx.x;  // 0..32767
  const int b = i >> 10, col = i & 1023;
  const int dir = col >> 9, jj = col & 511;
  const size_t se = ((size_t)dir * 32 + b) * 512 + jj;
  h0[(size_t)b * 1024 + col] = ench[se];          // layer0, parity0
  c0[(size_t)b * 1024 + col] = encc[se];          // layer0
  h1[(size_t)b * 1024 + col] = ench[65536 + se];  // layer1, parity0
  c1[(size_t)b * 1024 + col] = encc[32768 + se];  // layer1
}

// ---------------------------------------------------------------------------
extern "C" void kernel_launch(void* const* d_in, const int* in_sizes, int n_in,
                              void* d_out, int out_size, void* d_ws, size_t ws_size,
                              hipStream_t stream) {
  const int* x = (const int*)d_in[0];
  const int* y = (const int*)d_in[1];
  const float* src_emb = (const float*)d_in[2];
  const float* tgt_emb = (const float*)d_in[3];
  const float* enc_W_ih = (const float*)d_in[4];
  const float* enc_W_hh = (const float*)d_in[5];
  const float* enc_b_ih = (const float*)d_in[6];
  const float* enc_b_hh = (const float*)d_in[7];
  const float* dec_W_ih0 = (const float*)d_in[8];
  const float* dec_W_ih1 = (const float*)d_in[9];
  const float* dec_W_hh = (const float*)d_in[10];
  const float* dec_b_ih = (const float*)d_in[11];
  const float* dec_b_hh = (const float*)d_in[12];
  const float* W_out = (const float*)d_in[13];
  const float* b_out = (const float*)d_in[14];
  float* out = (float*)d_out;

  char* ws = (char*)d_ws;
  size_t off = 0;
  auto alloc = [&](size_t bytes) -> void* {
    void* p = ws + off;
    off += (bytes + 255) & ~(size_t)255;
    return p;
  };
  unsigned short* A0 = (unsigned short*)alloc(2048ull * 1024 * 2);
  unsigned short* seq1 = (unsigned short*)alloc(2048ull * 1024 * 2);
  unsigned short* Wih_bf = (unsigned short*)alloc(2ull * 4096 * 1024 * 2);
  unsigned short* Wih0_bf = (unsigned short*)alloc(4096ull * 2048 * 2);
  unsigned short* Wout_bf = (unsigned short*)alloc(32000ull * 1024 * 2);
  float* G = (float*)alloc(2048ull * 4096 * 4);
  unsigned short* inp0 = (unsigned short*)alloc(2048ull * 2048 * 2);
  unsigned short* H1all = (unsigned short*)alloc(2048ull * 1024 * 2);
  float* encbias = (float*)alloc(2ull * 4096 * 4);
  float* decdb = (float*)alloc(2ull * 4096 * 4);
  float* ench = (float*)alloc(2ull * 2 * 2 * 32 * 512 * 4);  // [l][p][d][b][j]
  float* encc = (float*)alloc(2ull * 2 * 32 * 512 * 4);      // [l][d][b][j] (adjacent to ench)
  float* h0buf = (float*)alloc(2ull * 32 * 1024 * 4);
  float* c0buf = (float*)alloc(32ull * 1024 * 4);
  float* h1buf = (float*)alloc(2ull * 32 * 1024 * 4);
  float* c1buf = (float*)alloc(32ull * 1024 * 4);
  if (off > ws_size) return;  // insufficient workspace -> visible as absmax failure

  // weight conversions + bias combines + embeddings
  cvt_bf16<<<1024, 256, 0, stream>>>(enc_W_ih, Wih_bf, (2ll * 4096 * 1024) / 4);
  cvt_bf16<<<1024, 256, 0, stream>>>(dec_W_ih0, Wih0_bf, (4096ll * 2048) / 4);
  cvt_bf16<<<2048, 256, 0, stream>>>(W_out, Wout_bf, (32000ll * 1024) / 4);
  bias_comb<<<32, 256, 0, stream>>>(enc_b_ih, enc_b_hh, encbias, 8192);
  bias_comb<<<32, 256, 0, stream>>>(dec_b_ih, dec_b_hh, decdb, 8192);
  embed_src<<<2048, 256, 0, stream>>>(x, src_emb, A0);
  embed_tgt<<<2048, 256, 0, stream>>>(y, tgt_emb, inp0);
  hipMemsetAsync(ench, 0, (2ull * 2 * 2 * 32 * 512 + 2ull * 2 * 32 * 512) * 4, stream);
  hipMemsetAsync(H1all + 2016ull * 1024, 0, 32ull * 1024 * 2, stream);

  // ---- encoder layer 0 ----
  gemm_bf16<<<dim3(32, 16), 256, 0, stream>>>(A0, Wih_bf, G, encbias, 1024, 4096, 2048, 0);
  for (int t = 0; t < 64; t++)
    enc_step<<<256, 128, 0, stream>>>(G, enc_W_hh, ench, encc, seq1, t);
  // ---- encoder layer 1 (output seq not needed; only final states) ----
  gemm_bf16<<<dim3(32, 16), 256, 0, stream>>>(seq1, Wih_bf + 4096ull * 1024, G,
                                              encbias + 4096, 1024, 4096, 2048, 0);
  for (int t = 0; t < 64; t++)
    enc_step<<<256, 128, 0, stream>>>(G, enc_W_hh + 2ull * 2048 * 512, ench + 65536,
                                      encc + 32768, nullptr, t);

  // ---- decoder setup ----
  dec_init<<<128, 256, 0, stream>>>(ench, encc, h0buf, c0buf, h1buf, c1buf);
  fill_ctx<<<2016, 256, 0, stream>>>(ench + 65536, inp0);
  gemm_bf16<<<dim3(32, 16), 256, 0, stream>>>(inp0, Wih0_bf, G, decdb, 2048, 4096, 2048, 0);

  // ---- decoder recurrence ----
  for (int t = 0; t < 63; t++) {
    dec_step0<<<256, 128, 0, stream>>>(G, dec_W_hh, h0buf, c0buf, t);
    dec_step1<<<256, 128, 0, stream>>>(dec_W_ih1, dec_W_hh + 4096ull * 1024, decdb + 4096,
                                       h0buf, h1buf, c1buf, H1all, t);
  }

  // ---- logits ----
  gemm_bf16<<<dim3(250, 16), 256, 0, stream>>>(H1all, Wout_bf, out, b_out, 1024, 32000,
                                               2016, 1);
}

// Round 2
// 4761.689 us; speedup vs baseline: 2.2553x; 2.2553x over previous
//
#include <hip/hip_runtime.h>

typedef __attribute__((ext_vector_type(8))) short short8;
typedef __attribute__((ext_vector_type(4))) float f32x4;

#define DEVINL __device__ __forceinline__

DEVINL unsigned short f2bf(float f) {
  unsigned int u = __builtin_bit_cast(unsigned int, f);
  unsigned int r = u + 0x7FFFu + ((u >> 16) & 1u);  // RNE
  return (unsigned short)(r >> 16);
}
DEVINL float bf2f(unsigned short u) {
  unsigned int x = ((unsigned int)u) << 16;
  return __builtin_bit_cast(float, x);
}
DEVINL float sig_(float x) { return 1.f / (1.f + __expf(-x)); }
DEVINL float tanh_(float x) { return 2.f / (1.f + __expf(-2.f * x)) - 1.f; }

DEVINL void gld16(void* lds, const void* g) {
  __builtin_amdgcn_global_load_lds(
      (const __attribute__((address_space(1))) unsigned int*)g,
      (__attribute__((address_space(3))) unsigned int*)lds, 16, 0, 0);
}

// ---------------------------------------------------------------------------
// bf16 GEMM: C[M,N] = A[M,K] @ Bt[N,K]^T + bias[N]
// 128x128 tile, BK=32, 4 waves (2x2 of 64x64), 16x16x32 bf16 MFMA.
// mode 0: f32 C[m*N+n]. mode 1: logits scatter f32 (m=(t*32+b) ->
//         C[b*63*32000 + t*32000 + n]). mode 2: bf16 C[m*N+n].
// ---------------------------------------------------------------------------
__global__ __launch_bounds__(256) void gemm_bf16(
    const unsigned short* __restrict__ A, const unsigned short* __restrict__ Bt,
    void* __restrict__ C, const float* __restrict__ bias,
    int K, int N, int Mvalid, int mode) {
  __shared__ unsigned short lA[512 * 8];
  __shared__ unsigned short lB[512 * 8];
  const int tid = threadIdx.x;
  const int lane = tid & 63, wid = tid >> 6;
  const int wm = wid >> 1, wn = wid & 1;
  const int bn = blockIdx.x, bm = blockIdx.y;
  const size_t K_ = (size_t)K;

  const int s0 = tid, s1 = tid + 256;
  const int r0 = s0 & 127, kb0 = s0 >> 7;
  const int r1 = s1 & 127, kb1 = s1 >> 7;
  const unsigned short* gA0 = A + (size_t)(bm * 128 + r0) * K_ + kb0 * 8;
  const unsigned short* gA1 = A + (size_t)(bm * 128 + r1) * K_ + kb1 * 8;
  const unsigned short* gB0 = Bt + (size_t)(bn * 128 + r0) * K_ + kb0 * 8;
  const unsigned short* gB1 = Bt + (size_t)(bn * 128 + r1) * K_ + kb1 * 8;
  unsigned short* lA0 = lA + (size_t)(wid * 64) * 8;
  unsigned short* lA1 = lA + (size_t)(256 + wid * 64) * 8;
  unsigned short* lB0 = lB + (size_t)(wid * 64) * 8;
  unsigned short* lB1 = lB + (size_t)(256 + wid * 64) * 8;

  f32x4 acc[4][4] = {};
  const int kg = lane >> 4, lr = lane & 15;

  for (int kt = 0; kt < K; kt += 32) {
    gld16(lA0, gA0 + kt);
    gld16(lA1, gA1 + kt);
    gld16(lB0, gB0 + kt);
    gld16(lB1, gB1 + kt);
    __syncthreads();
    short8 af[4], bfr[4];
#pragma unroll
    for (int fm = 0; fm < 4; fm++)
      af[fm] = *(const short8*)&lA[(size_t)(kg * 128 + wm * 64 + fm * 16 + lr) * 8];
#pragma unroll
    for (int fn = 0; fn < 4; fn++)
      bfr[fn] = *(const short8*)&lB[(size_t)(kg * 128 + wn * 64 + fn * 16 + lr) * 8];
#pragma unroll
    for (int fm = 0; fm < 4; fm++)
#pragma unroll
      for (int fn = 0; fn < 4; fn++)
        acc[fm][fn] =
            __builtin_amdgcn_mfma_f32_16x16x32_bf16(af[fm], bfr[fn], acc[fm][fn], 0, 0, 0);
    __syncthreads();
  }

#pragma unroll
  for (int fn = 0; fn < 4; fn++) {
    const int col = bn * 128 + wn * 64 + fn * 16 + lr;
    const float bv = bias ? bias[col] : 0.f;
#pragma unroll
    for (int fm = 0; fm < 4; fm++) {
      const int row0 = bm * 128 + wm * 64 + fm * 16 + kg * 4;
#pragma unroll
      for (int r = 0; r < 4; r++) {
        const int m = row0 + r;
        if (m < Mvalid) {
          const float v = acc[fm][fn][r] + bv;
          if (mode == 0) {
            ((float*)C)[(size_t)m * N + col] = v;
          } else if (mode == 1) {
            const int b = m & 31, t = m >> 5;
            ((float*)C)[(size_t)b * 2016000 + (size_t)t * 32000 + col] = v;
          } else {
            ((unsigned short*)C)[(size_t)m * N + col] = f2bf(v);
          }
        }
      }
    }
  }
}

// ---------------------------------------------------------------------------
// MFMA LSTM step kernels. One wave (64 thr) per block; block owns a 16-wide
// j-tile and all 4 gates; epilogue applies the LSTM nonlinearity in-register.
// A = h (bf16), B = recurrent weights (bf16, [4Hd][K] row-major), C += gates.
// ---------------------------------------------------------------------------

#define MFMA8(a0, a1, b0, b1, b2, b3)                                                \
  acc[0][0] = __builtin_amdgcn_mfma_f32_16x16x32_bf16(a0, b0, acc[0][0], 0, 0, 0);   \
  acc[1][0] = __builtin_amdgcn_mfma_f32_16x16x32_bf16(a1, b0, acc[1][0], 0, 0, 0);   \
  acc[0][1] = __builtin_amdgcn_mfma_f32_16x16x32_bf16(a0, b1, acc[0][1], 0, 0, 0);   \
  acc[1][1] = __builtin_amdgcn_mfma_f32_16x16x32_bf16(a1, b1, acc[1][1], 0, 0, 0);   \
  acc[0][2] = __builtin_amdgcn_mfma_f32_16x16x32_bf16(a0, b2, acc[0][2], 0, 0, 0);   \
  acc[1][2] = __builtin_amdgcn_mfma_f32_16x16x32_bf16(a1, b2, acc[1][2], 0, 0, 0);   \
  acc[0][3] = __builtin_amdgcn_mfma_f32_16x16x32_bf16(a0, b3, acc[0][3], 0, 0, 0);   \
  acc[1][3] = __builtin_amdgcn_mfma_f32_16x16x32_bf16(a1, b3, acc[1][3], 0, 0, 0);

// Encoder: grid 64 (dir*32 + jtile), block 64. K=512, Hd=512, both dirs.
__global__ __launch_bounds__(64) void enc_step_mfma(
    const unsigned short* __restrict__ Hcur, unsigned short* __restrict__ Hnext,
    const unsigned short* __restrict__ Whh, const unsigned short* __restrict__ G,
    float* __restrict__ c, unsigned short* __restrict__ seq_out, int t) {
  const int lane = threadIdx.x;
  const int lr = lane & 15, kg = lane >> 4;
  const int dir = blockIdx.x >> 5;
  const int j0 = (blockIdx.x & 31) * 16;
  const unsigned short* Hd = Hcur + dir * (32 * 512);
  const unsigned short* Wd = Whh + (size_t)dir * 2048 * 512;
  const unsigned short* pA0 = Hd + lr * 512 + kg * 8;
  const unsigned short* pA1 = pA0 + 16 * 512;
  const unsigned short* pB0 = Wd + (size_t)(j0 + lr) * 512 + kg * 8;
  const unsigned short* pB1 = pB0 + 512 * 512;
  const unsigned short* pB2 = pB0 + 1024 * 512;
  const unsigned short* pB3 = pB0 + 1536 * 512;
  f32x4 acc[2][4] = {};
#pragma unroll 8
  for (int kt = 0; kt < 16; kt++) {
    const int o = kt * 32;
    short8 a0 = *(const short8*)(pA0 + o);
    short8 a1 = *(const short8*)(pA1 + o);
    short8 b0 = *(const short8*)(pB0 + o);
    short8 b1 = *(const short8*)(pB1 + o);
    short8 b2 = *(const short8*)(pB2 + o);
    short8 b3 = *(const short8*)(pB3 + o);
    MFMA8(a0, a1, b0, b1, b2, b3)
  }
  const int s_idx = dir ? (63 - t) : t;
  const int j = j0 + lr;
  float* cd = c + dir * (32 * 512);
  unsigned short* Hn = Hnext + dir * (32 * 512);
#pragma unroll
  for (int mt = 0; mt < 2; mt++) {
#pragma unroll
    for (int r = 0; r < 4; r++) {
      const int brow = mt * 16 + kg * 4 + r;
      const unsigned short* Gr = G + (size_t)(s_idx * 32 + brow) * 4096 + dir * 2048;
      const float gi = bf2f(Gr[j]) + acc[mt][0][r];
      const float gf = bf2f(Gr[512 + j]) + acc[mt][1][r];
      const float gg = bf2f(Gr[1024 + j]) + acc[mt][2][r];
      const float go = bf2f(Gr[1536 + j]) + acc[mt][3][r];
      const int ci = brow * 512 + j;
      const float cn = sig_(gf) * cd[ci] + sig_(gi) * tanh_(gg);
      const float hn = sig_(go) * tanh_(cn);
      cd[ci] = cn;
      const unsigned short hb = f2bf(hn);
      Hn[ci] = hb;
      if (seq_out) seq_out[(size_t)(s_idx * 32 + brow) * 1024 + dir * 512 + j] = hb;
    }
  }
}

// Decoder cell0: grid 64 (jtile), block 64. K=1024, Hd=1024.
__global__ __launch_bounds__(64) void dec0_step_mfma(
    const unsigned short* __restrict__ Hcur, unsigned short* __restrict__ Hnext,
    const unsigned short* __restrict__ W, const unsigned short* __restrict__ G,
    float* __restrict__ c0, int t) {
  const int lane = threadIdx.x;
  const int lr = lane & 15, kg = lane >> 4;
  const int j0 = blockIdx.x * 16;
  const unsigned short* pA0 = Hcur + lr * 1024 + kg * 8;
  const unsigned short* pA1 = pA0 + 16 * 1024;
  const unsigned short* pB0 = W + (size_t)(j0 + lr) * 1024 + kg * 8;
  const unsigned short* pB1 = pB0 + (size_t)1024 * 1024;
  const unsigned short* pB2 = pB0 + (size_t)2048 * 1024;
  const unsigned short* pB3 = pB0 + (size_t)3072 * 1024;
  f32x4 acc[2][4] = {};
#pragma unroll 8
  for (int kt = 0; kt < 32; kt++) {
    const int o = kt * 32;
    short8 a0 = *(const short8*)(pA0 + o);
    short8 a1 = *(const short8*)(pA1 + o);
    short8 b0 = *(const short8*)(pB0 + o);
    short8 b1 = *(const short8*)(pB1 + o);
    short8 b2 = *(const short8*)(pB2 + o);
    short8 b3 = *(const short8*)(pB3 + o);
    MFMA8(a0, a1, b0, b1, b2, b3)
  }
  const int j = j0 + lr;
#pragma unroll
  for (int mt = 0; mt < 2; mt++) {
#pragma unroll
    for (int r = 0; r < 4; r++) {
      const int brow = mt * 16 + kg * 4 + r;
      const unsigned short* Gr = G + (size_t)(t * 32 + brow) * 4096;
      const float gi = bf2f(Gr[j]) + acc[mt][0][r];
      const float gf = bf2f(Gr[1024 + j]) + acc[mt][1][r];
      const float gg = bf2f(Gr[2048 + j]) + acc[mt][2][r];
      const float go = bf2f(Gr[3072 + j]) + acc[mt][3][r];
      const int ci = brow * 1024 + j;
      const float cn = sig_(gf) * c0[ci] + sig_(gi) * tanh_(gg);
      const float hn = sig_(go) * tanh_(cn);
      c0[ci] = cn;
      Hnext[ci] = f2bf(hn);
    }
  }
}

// Decoder cell1: A = [h0_new | h1_prev] (K=2048), B = packed [Wih1|Whh1].
__global__ __launch_bounds__(64) void dec1_step_mfma(
    const unsigned short* __restrict__ H0new, const unsigned short* __restrict__ H1cur,
    unsigned short* __restrict__ H1next, const unsigned short* __restrict__ Wc,
    const float* __restrict__ db1, float* __restrict__ c1,
    unsigned short* __restrict__ H1all, int t) {
  const int lane = threadIdx.x;
  const int lr = lane & 15, kg = lane >> 4;
  const int j0 = blockIdx.x * 16;
  const unsigned short* pB0 = Wc + (size_t)(j0 + lr) * 2048 + kg * 8;
  const unsigned short* pB1 = pB0 + (size_t)1024 * 2048;
  const unsigned short* pB2 = pB0 + (size_t)2048 * 2048;
  const unsigned short* pB3 = pB0 + (size_t)3072 * 2048;
  f32x4 acc[2][4] = {};
  {
    const unsigned short* pA0 = H0new + lr * 1024 + kg * 8;
    const unsigned short* pA1 = pA0 + 16 * 1024;
#pragma unroll 8
    for (int kt = 0; kt < 32; kt++) {
      const int o = kt * 32;
      short8 a0 = *(const short8*)(pA0 + o);
      short8 a1 = *(const short8*)(pA1 + o);
      short8 b0 = *(const short8*)(pB0 + o);
      short8 b1 = *(const short8*)(pB1 + o);
      short8 b2 = *(const short8*)(pB2 + o);
      short8 b3 = *(const short8*)(pB3 + o);
      MFMA8(a0, a1, b0, b1, b2, b3)
    }
  }
  {
    const unsigned short* pA0 = H1cur + lr * 1024 + kg * 8;
    const unsigned short* pA1 = pA0 + 16 * 1024;
#pragma unroll 8
    for (int kt = 32; kt < 64; kt++) {
      const int o = kt * 32, oa = (kt - 32) * 32;
      short8 a0 = *(const short8*)(pA0 + oa);
      short8 a1 = *(const short8*)(pA1 + oa);
      short8 b0 = *(const short8*)(pB0 + o);
      short8 b1 = *(const short8*)(pB1 + o);
      short8 b2 = *(const short8*)(pB2 + o);
      short8 b3 = *(const short8*)(pB3 + o);
      MFMA8(a0, a1, b0, b1, b2, b3)
    }
  }
  const int j = j0 + lr;
#pragma unroll
  for (int mt = 0; mt < 2; mt++) {
#pragma unroll
    for (int r = 0; r < 4; r++) {
      const int brow = mt * 16 + kg * 4 + r;
      const float gi = db1[j] + acc[mt][0][r];
      const float gf = db1[1024 + j] + acc[mt][1][r];
      const float gg = db1[2048 + j] + acc[mt][2][r];
      const float go = db1[3072 + j] + acc[mt][3][r];
      const int ci = brow * 1024 + j;
      const float cn = sig_(gf) * c1[ci] + sig_(gi) * tanh_(gg);
      const float hn = sig_(go) * tanh_(cn);
      c1[ci] = cn;
      const unsigned short hb = f2bf(hn);
      H1next[ci] = hb;
      H1all[(size_t)(t * 32 + brow) * 1024 + j] = hb;
    }
  }
}

// ---------------------------------------------------------------------------
// Setup kernels
// ---------------------------------------------------------------------------
__global__ void cvt_bf16(const float* __restrict__ in, unsigned short* __restrict__ out,
                         long n4) {
  long i = (long)blockIdx.x * blockDim.x + threadIdx.x;
  const long stride = (long)gridDim.x * blockDim.x;
  for (; i < n4; i += stride) {
    f32x4 v = *(const f32x4*)&in[i * 4];
    ushort4 o = {f2bf(v.x), f2bf(v.y), f2bf(v.z), f2bf(v.w)};
    *(ushort4*)&out[i * 4] = o;
  }
}

// Wc[n][k]: k<1024 from Wih1[n][k], else Whh1[n][k-1024]; grid 4096 x 256
__global__ void pack_wc1(const float* __restrict__ Wih1, const float* __restrict__ Whh1,
                         unsigned short* __restrict__ Wc) {
  const int n = blockIdx.x;
  const int c = threadIdx.x * 8;
  const float* src = (c < 1024) ? (Wih1 + (size_t)n * 1024 + c)
                                : (Whh1 + (size_t)n * 1024 + (c - 1024));
  f32x4 v0 = *(const f32x4*)src;
  f32x4 v1 = *(const f32x4*)(src + 4);
  ushort4 o0 = {f2bf(v0.x), f2bf(v0.y), f2bf(v0.z), f2bf(v0.w)};
  ushort4 o1 = {f2bf(v1.x), f2bf(v1.y), f2bf(v1.z), f2bf(v1.w)};
  *(ushort4*)&Wc[(size_t)n * 2048 + c] = o0;
  *(ushort4*)&Wc[(size_t)n * 2048 + c + 4] = o1;
}

__global__ void bias_comb(const float* __restrict__ a, const float* __restrict__ b,
                          float* __restrict__ out, int n) {
  int i = blockIdx.x * blockDim.x + threadIdx.x;
  if (i < n) out[i] = a[i] + b[i];
}

__global__ void embed_src(const int* __restrict__ x, const float* __restrict__ emb,
                          unsigned short* __restrict__ A0) {
  const int row = blockIdx.x;
  const int s = row >> 5, b = row & 31;
  const int tok = x[b * 64 + (63 - s)];
  const int col = threadIdx.x * 4;
  f32x4 v = *(const f32x4*)(emb + (size_t)tok * 1024 + col);
  ushort4 o = {f2bf(v.x), f2bf(v.y), f2bf(v.z), f2bf(v.w)};
  *(ushort4*)&A0[(size_t)row * 1024 + col] = o;
}

__global__ void embed_tgt(const int* __restrict__ y, const float* __restrict__ emb,
                          unsigned short* __restrict__ inp0) {
  const int row = blockIdx.x;
  const int col = threadIdx.x * 4;
  ushort4 o = {0, 0, 0, 0};
  if (row < 2016) {
    const int t = row >> 5, b = row & 31;
    const int tok = y[b * 64 + t];
    f32x4 v = *(const f32x4*)(emb + (size_t)tok * 1024 + col);
    o = ushort4{f2bf(v.x), f2bf(v.y), f2bf(v.z), f2bf(v.w)};
  } else {
    *(ushort4*)&inp0[(size_t)row * 2048 + 1024 + col] = o;
  }
  *(ushort4*)&inp0[(size_t)row * 2048 + col] = o;
}

// ctx half of inp0 from enc layer-1 final h (bf16); grid 2016 x 256
__global__ void fill_ctx2(const unsigned short* __restrict__ Hl1,
                          unsigned short* __restrict__ inp0) {
  const int row = blockIdx.x;
  const int b = row & 31;
  const int col = threadIdx.x * 4;
  const int dir = col >> 9, jj = col & 511;
  ushort4 v = *(const ushort4*)(Hl1 + ((size_t)dir * 32 + b) * 512 + jj);
  *(ushort4*)&inp0[(size_t)row * 2048 + 1024 + col] = v;
}

// decoder state init; grid 128 x 256
__global__ void dec_init2(const unsigned short* __restrict__ Hl0,
                          const unsigned short* __restrict__ Hl1,
                          const float* __restrict__ Cl0, const float* __restrict__ Cl1,
                          unsigned short* __restrict__ H0, unsigned short* __restrict__ H1,
                          float* __restrict__ c0, float* __restrict__ c1) {
  const int i = blockIdx.x * 256 + threadIdx.x;
  const int b = i >> 10, col = i & 1023;
  const int dir = col >> 9, jj = col & 511;
  const int se = (dir * 32 + b) * 512 + jj;
  const int de = b * 1024 + col;
  H0[de] = Hl0[se];
  H1[de] = Hl1[se];
  c0[de] = Cl0[se];
  c1[de] = Cl1[se];
}

// ---------------------------------------------------------------------------
extern "C" void kernel_launch(void* const* d_in, const int* in_sizes, int n_in,
                              void* d_out, int out_size, void* d_ws, size_t ws_size,
                              hipStream_t stream) {
  const int* x = (const int*)d_in[0];
  const int* y = (const int*)d_in[1];
  const float* src_emb = (const float*)d_in[2];
  const float* tgt_emb = (const float*)d_in[3];
  const float* enc_W_ih = (const float*)d_in[4];
  const float* enc_W_hh = (const float*)d_in[5];
  const float* enc_b_ih = (const float*)d_in[6];
  const float* enc_b_hh = (const float*)d_in[7];
  const float* dec_W_ih0 = (const float*)d_in[8];
  const float* dec_W_ih1 = (const float*)d_in[9];
  const float* dec_W_hh = (const float*)d_in[10];
  const float* dec_b_ih = (const float*)d_in[11];
  const float* dec_b_hh = (const float*)d_in[12];
  const float* W_out = (const float*)d_in[13];
  const float* b_out = (const float*)d_in[14];
  float* out = (float*)d_out;

  char* ws = (char*)d_ws;
  size_t off = 0;
  auto alloc = [&](size_t bytes) -> void* {
    void* p = ws + off;
    off += (bytes + 255) & ~(size_t)255;
    return p;
  };
  unsigned short* A0 = (unsigned short*)alloc(2048ull * 1024 * 2);
  unsigned short* seq1 = (unsigned short*)alloc(2048ull * 1024 * 2);
  unsigned short* Wih_bf = (unsigned short*)alloc(2ull * 4096 * 1024 * 2);
  unsigned short* Wih0_bf = (unsigned short*)alloc(4096ull * 2048 * 2);
  unsigned short* Wout_bf = (unsigned short*)alloc(32000ull * 1024 * 2);
  unsigned short* G = (unsigned short*)alloc(2048ull * 4096 * 2);  // bf16 gates
  unsigned short* inp0 = (unsigned short*)alloc(2048ull * 2048 * 2);
  unsigned short* H1all = (unsigned short*)alloc(2048ull * 1024 * 2);
  unsigned short* Whh_enc_bf = (unsigned short*)alloc(2ull * 2 * 2048 * 512 * 2);
  unsigned short* Whh0_bf = (unsigned short*)alloc(4096ull * 1024 * 2);
  unsigned short* Wc1_bf = (unsigned short*)alloc(4096ull * 2048 * 2);
  float* encbias = (float*)alloc(2ull * 4096 * 4);
  float* decdb = (float*)alloc(2ull * 4096 * 4);
  // zero-init block (contiguous): Hp_l0, Hp_l1, c_l0, c_l1
  unsigned short* Hp_l0 = (unsigned short*)alloc(2ull * 2 * 32 * 512 * 2);  // [p][d][b][j]
  unsigned short* Hp_l1 = (unsigned short*)alloc(2ull * 2 * 32 * 512 * 2);
  float* c_l0 = (float*)alloc(2ull * 32 * 512 * 4);  // [d][b][j]
  float* c_l1 = (float*)alloc(2ull * 32 * 512 * 4);
  unsigned short* H0pair = (unsigned short*)alloc(2ull * 32 * 1024 * 2);
  unsigned short* H1pair = (unsigned short*)alloc(2ull * 32 * 1024 * 2);
  float* c0buf = (float*)alloc(32ull * 1024 * 4);
  float* c1buf = (float*)alloc(32ull * 1024 * 4);
  if (off > ws_size) return;

  // ---- setup: weight converts, biases, embeddings, state zeroing ----
  cvt_bf16<<<1024, 256, 0, stream>>>(enc_W_ih, Wih_bf, (2ll * 4096 * 1024) / 4);
  cvt_bf16<<<1024, 256, 0, stream>>>(dec_W_ih0, Wih0_bf, (4096ll * 2048) / 4);
  cvt_bf16<<<2048, 256, 0, stream>>>(W_out, Wout_bf, (32000ll * 1024) / 4);
  cvt_bf16<<<1024, 256, 0, stream>>>(enc_W_hh, Whh_enc_bf, (2ll * 2 * 2048 * 512) / 4);
  cvt_bf16<<<1024, 256, 0, stream>>>(dec_W_hh, Whh0_bf, (4096ll * 1024) / 4);
  pack_wc1<<<4096, 256, 0, stream>>>(dec_W_ih1, dec_W_hh + 4096ll * 1024, Wc1_bf);
  bias_comb<<<32, 256, 0, stream>>>(enc_b_ih, enc_b_hh, encbias, 8192);
  bias_comb<<<32, 256, 0, stream>>>(dec_b_ih, dec_b_hh, decdb, 8192);
  embed_src<<<2048, 256, 0, stream>>>(x, src_emb, A0);
  embed_tgt<<<2048, 256, 0, stream>>>(y, tgt_emb, inp0);
  hipMemsetAsync(Hp_l0, 0, (4ull * 2 * 32 * 512) * 2 + (4ull * 32 * 512) * 4, stream);

  // ---- encoder layer 0 ----
  gemm_bf16<<<dim3(32, 16), 256, 0, stream>>>(A0, Wih_bf, G, encbias, 1024, 4096, 2048, 2);
  for (int t = 0; t < 64; t++)
    enc_step_mfma<<<64, 64, 0, stream>>>(Hp_l0 + (t & 1) * 32768, Hp_l0 + ((t & 1) ^ 1) * 32768,
                                         Whh_enc_bf, G, c_l0, seq1, t);
  // ---- encoder layer 1 ----
  gemm_bf16<<<dim3(32, 16), 256, 0, stream>>>(seq1, Wih_bf + 4096ull * 1024, G,
                                              encbias + 4096, 1024, 4096, 2048, 2);
  for (int t = 0; t < 64; t++)
    enc_step_mfma<<<64, 64, 0, stream>>>(Hp_l1 + (t & 1) * 32768, Hp_l1 + ((t & 1) ^ 1) * 32768,
                                         Whh_enc_bf + 2ull * 2048 * 512, G, c_l1, nullptr, t);

  // ---- decoder setup ----
  dec_init2<<<128, 256, 0, stream>>>(Hp_l0, Hp_l1, c_l0, c_l1, H0pair, H1pair, c0buf, c1buf);
  fill_ctx2<<<2016, 256, 0, stream>>>(Hp_l1, inp0);
  gemm_bf16<<<dim3(32, 16), 256, 0, stream>>>(inp0, Wih0_bf, G, decdb, 2048, 4096, 2048, 2);
  hipMemsetAsync(H1all + 2016ull * 1024, 0, 32ull * 1024 * 2, stream);

  // ---- decoder recurrence ----
  for (int t = 0; t < 63; t++) {
    const int p = t & 1;
    dec0_step_mfma<<<64, 64, 0, stream>>>(H0pair + p * 32768, H0pair + (p ^ 1) * 32768,
                                          Whh0_bf, G, c0buf, t);
    dec1_step_mfma<<<64, 64, 0, stream>>>(H0pair + (p ^ 1) * 32768, H1pair + p * 32768,
                                          H1pair + (p ^ 1) * 32768, Wc1_bf, decdb + 4096,
                                          c1buf, H1all, t);
  }

  // ---- logits ----
  gemm_bf16<<<dim3(250, 16), 256, 0, stream>>>(H1all, Wout_bf, out, b_out, 1024, 32000,
                                               2016, 1);
}

// Round 3
// 4306.712 us; speedup vs baseline: 2.4936x; 1.1056x over previous
//
#include <hip/hip_runtime.h>

typedef __attribute__((ext_vector_type(8))) short short8;
typedef __attribute__((ext_vector_type(4))) float f32x4;

#define DEVINL __device__ __forceinline__

DEVINL unsigned short f2bf(float f) {
  unsigned int u = __builtin_bit_cast(unsigned int, f);
  unsigned int r = u + 0x7FFFu + ((u >> 16) & 1u);  // RNE
  return (unsigned short)(r >> 16);
}
DEVINL float bf2f(unsigned short u) {
  unsigned int x = ((unsigned int)u) << 16;
  return __builtin_bit_cast(float, x);
}
DEVINL float sig_(float x) { return 1.f / (1.f + __expf(-x)); }
DEVINL float tanh_(float x) { return 2.f / (1.f + __expf(-2.f * x)) - 1.f; }

DEVINL void gld16(void* lds, const void* g) {
  __builtin_amdgcn_global_load_lds(
      (const __attribute__((address_space(1))) unsigned int*)g,
      (__attribute__((address_space(3))) unsigned int*)lds, 16, 0, 0);
}

// ---- device-scope sense-reversing grid barrier (co-resident grids only) ----
DEVINL void grid_bar(int* cnt, int* flag, int nb, int& sense) {
  __syncthreads();  // drains each wave's vmcnt before arrive
  if (threadIdx.x == 0) {
    sense ^= 1;
    __threadfence();  // publish this block's stores agent-wide
    if (__hip_atomic_fetch_add(cnt, 1, __ATOMIC_ACQ_REL, __HIP_MEMORY_SCOPE_AGENT) == nb - 1) {
      __hip_atomic_store(cnt, 0, __ATOMIC_RELAXED, __HIP_MEMORY_SCOPE_AGENT);
      __hip_atomic_store(flag, sense, __ATOMIC_RELEASE, __HIP_MEMORY_SCOPE_AGENT);
    } else {
      while (__hip_atomic_load(flag, __ATOMIC_ACQUIRE, __HIP_MEMORY_SCOPE_AGENT) != sense) {
        __builtin_amdgcn_s_sleep(2);
      }
    }
    __threadfence();  // invalidate caches before consuming others' data
  }
  __syncthreads();
}

// ---------------------------------------------------------------------------
// bf16 GEMM: C[M,N] = A[M,K] @ Bt[N,K]^T + bias[N]
// 128x128 tile, BK=32, 4 waves, 16x16x32 bf16 MFMA.
// mode 0: f32 C. mode 1: logits scatter f32. mode 2: bf16 C.
// ---------------------------------------------------------------------------
__global__ __launch_bounds__(256) void gemm_bf16(
    const unsigned short* __restrict__ A, const unsigned short* __restrict__ Bt,
    void* __restrict__ C, const float* __restrict__ bias,
    int K, int N, int Mvalid, int mode) {
  __shared__ unsigned short lA[512 * 8];
  __shared__ unsigned short lB[512 * 8];
  const int tid = threadIdx.x;
  const int lane = tid & 63, wid = tid >> 6;
  const int wm = wid >> 1, wn = wid & 1;
  const int bn = blockIdx.x, bm = blockIdx.y;
  const size_t K_ = (size_t)K;

  const int s0 = tid, s1 = tid + 256;
  const int r0 = s0 & 127, kb0 = s0 >> 7;
  const int r1 = s1 & 127, kb1 = s1 >> 7;
  const unsigned short* gA0 = A + (size_t)(bm * 128 + r0) * K_ + kb0 * 8;
  const unsigned short* gA1 = A + (size_t)(bm * 128 + r1) * K_ + kb1 * 8;
  const unsigned short* gB0 = Bt + (size_t)(bn * 128 + r0) * K_ + kb0 * 8;
  const unsigned short* gB1 = Bt + (size_t)(bn * 128 + r1) * K_ + kb1 * 8;
  unsigned short* lA0 = lA + (size_t)(wid * 64) * 8;
  unsigned short* lA1 = lA + (size_t)(256 + wid * 64) * 8;
  unsigned short* lB0 = lB + (size_t)(wid * 64) * 8;
  unsigned short* lB1 = lB + (size_t)(256 + wid * 64) * 8;

  f32x4 acc[4][4] = {};
  const int kg = lane >> 4, lr = lane & 15;

  for (int kt = 0; kt < K; kt += 32) {
    gld16(lA0, gA0 + kt);
    gld16(lA1, gA1 + kt);
    gld16(lB0, gB0 + kt);
    gld16(lB1, gB1 + kt);
    __syncthreads();
    short8 af[4], bfr[4];
#pragma unroll
    for (int fm = 0; fm < 4; fm++)
      af[fm] = *(const short8*)&lA[(size_t)(kg * 128 + wm * 64 + fm * 16 + lr) * 8];
#pragma unroll
    for (int fn = 0; fn < 4; fn++)
      bfr[fn] = *(const short8*)&lB[(size_t)(kg * 128 + wn * 64 + fn * 16 + lr) * 8];
#pragma unroll
    for (int fm = 0; fm < 4; fm++)
#pragma unroll
      for (int fn = 0; fn < 4; fn++)
        acc[fm][fn] =
            __builtin_amdgcn_mfma_f32_16x16x32_bf16(af[fm], bfr[fn], acc[fm][fn], 0, 0, 0);
    __syncthreads();
  }

#pragma unroll
  for (int fn = 0; fn < 4; fn++) {
    const int col = bn * 128 + wn * 64 + fn * 16 + lr;
    const float bv = bias ? bias[col] : 0.f;
#pragma unroll
    for (int fm = 0; fm < 4; fm++) {
      const int row0 = bm * 128 + wm * 64 + fm * 16 + kg * 4;
#pragma unroll
      for (int r = 0; r < 4; r++) {
        const int m = row0 + r;
        if (m < Mvalid) {
          const float v = acc[fm][fn][r] + bv;
          if (mode == 0) {
            ((float*)C)[(size_t)m * N + col] = v;
          } else if (mode == 1) {
            const int b = m & 31, t = m >> 5;
            ((float*)C)[(size_t)b * 2016000 + (size_t)t * 32000 + col] = v;
          } else {
            ((unsigned short*)C)[(size_t)m * N + col] = f2bf(v);
          }
        }
      }
    }
  }
}

// ---------------------------------------------------------------------------
// Persistent encoder layer. grid 64 (dir*32 + jtile16) x 128 thr, 64KB dyn LDS.
// LDS row r (0..63): gate g=r>>4, jl=r&15 -> Whh[dir] row g*512+j0+jl, XOR-swz.
// Wave w handles b-rows w*16..w*16+15. c-state in regs. 64 steps, 63 barriers.
// ---------------------------------------------------------------------------
__global__ __launch_bounds__(128, 1) void enc_persist(
    const unsigned short* __restrict__ Whh, const unsigned short* __restrict__ G,
    unsigned short* __restrict__ Hping, unsigned short* __restrict__ seq_out,
    float* __restrict__ c_out, int* cnt, int* flag) {
  extern __shared__ unsigned short lw[];
  const int tid = threadIdx.x;
  const int lane = tid & 63, w = tid >> 6;
  const int dir = (int)blockIdx.x >> 5, j0 = ((int)blockIdx.x & 31) * 16;
  const int lr = lane & 15, kg = lane >> 4;
  {
    const unsigned short* Wd = Whh + (size_t)dir * 2048 * 512;
    for (int it = 0; it < 32; it++) {
      const int idx = (it * 128 + tid) * 16;
      const int r = idx >> 10, o = idx & 1023;
      const unsigned short* src = Wd + (size_t)((r >> 4) * 512 + j0 + (r & 15)) * 512 + (o >> 1);
      *(short8*)((char*)lw + r * 1024 + (o ^ ((r & 7) << 4))) = *(const short8*)src;
    }
  }
  float cc[4] = {0.f, 0.f, 0.f, 0.f};
  int sense = 0;
  const int j = j0 + lr;
  __syncthreads();
  for (int t = 0; t < 64; t++) {
    const int p = t & 1;
    const unsigned short* hA =
        Hping + p * (2 * 32 * 512) + dir * (32 * 512) + (w * 16 + lr) * 512 + kg * 8;
    f32x4 acc[4] = {};
#pragma unroll
    for (int kc = 0; kc < 16; kc++) {
      short8 a = *(const short8*)(hA + kc * 32);
#pragma unroll
      for (int g = 0; g < 4; g++) {
        const int rr = g * 16 + lr;
        short8 bf = *(const short8*)((const char*)lw + rr * 1024 +
                                     ((kc * 64 + kg * 16) ^ ((rr & 7) << 4)));
        acc[g] = __builtin_amdgcn_mfma_f32_16x16x32_bf16(a, bf, acc[g], 0, 0, 0);
      }
    }
    const int s_idx = dir ? (63 - t) : t;
    unsigned short* Hw = Hping + (p ^ 1) * (2 * 32 * 512) + dir * (32 * 512);
#pragma unroll
    for (int r = 0; r < 4; r++) {
      const int b = w * 16 + kg * 4 + r;
      const unsigned short* Gr = G + (size_t)(s_idx * 32 + b) * 4096 + dir * 2048 + j;
      const float gi = bf2f(Gr[0]) + acc[0][r];
      const float gf = bf2f(Gr[512]) + acc[1][r];
      const float gg = bf2f(Gr[1024]) + acc[2][r];
      const float go = bf2f(Gr[1536]) + acc[3][r];
      const float cn = sig_(gf) * cc[r] + sig_(gi) * tanh_(gg);
      const float hn = sig_(go) * tanh_(cn);
      cc[r] = cn;
      const unsigned short hb = f2bf(hn);
      Hw[b * 512 + j] = hb;
      if (seq_out) seq_out[(size_t)(s_idx * 32 + b) * 1024 + dir * 512 + j] = hb;
    }
    if (t < 63) grid_bar(cnt, flag, 64, sense);
  }
#pragma unroll
  for (int r = 0; r < 4; r++)
    c_out[(dir * 32 + (w * 16 + kg * 4 + r)) * 512 + j] = cc[r];
}

// ---------------------------------------------------------------------------
// Persistent decoder: 192 blocks x 128 thr, 128KB dyn LDS, software-pipelined:
// iter k: blocks 0..63 run dec0 producing h0 state s_k (t=k, k<63);
//         blocks 64..191 run dec1 producing h1 state s'_{k-1} (t=k-1, k>=1).
// h0/h1 ping-pong parity: read k&1 / write ^1 (h0); dec1 h1 read (k&1)^1,
// write k&1. One barrier per iter (63 total).
// ---------------------------------------------------------------------------
__global__ __launch_bounds__(128, 1) void dec_persist(
    const unsigned short* __restrict__ Whh0, const unsigned short* __restrict__ Wc1,
    const unsigned short* __restrict__ G, const float* __restrict__ db1,
    const float* __restrict__ c0init, const float* __restrict__ c1init,
    unsigned short* __restrict__ h0ping, unsigned short* __restrict__ h1ping,
    unsigned short* __restrict__ H1all, int* cnt, int* flag) {
  extern __shared__ unsigned short lw[];
  const int tid = threadIdx.x;
  const int lane = tid & 63, w = tid >> 6;
  const int lr = lane & 15, kg = lane >> 4;
  const int bid = (int)blockIdx.x;
  int sense = 0;
  if (bid < 64) {
    // ---- dec0: jtile 16, all 4 gates local; LDS [64][1024] bf16 swz ----
    const int j0 = bid * 16, j = j0 + lr;
    for (int it = 0; it < 64; it++) {
      const int idx = (it * 128 + tid) * 16;
      const int r = idx >> 11, o = idx & 2047;
      const unsigned short* src =
          Whh0 + (size_t)((r >> 4) * 1024 + j0 + (r & 15)) * 1024 + (o >> 1);
      *(short8*)((char*)lw + r * 2048 + (o ^ ((r & 7) << 4))) = *(const short8*)src;
    }
    float cc[4];
#pragma unroll
    for (int r = 0; r < 4; r++) cc[r] = c0init[(w * 16 + kg * 4 + r) * 1024 + j];
    __syncthreads();
    for (int k = 0; k < 64; k++) {
      if (k < 63) {
        const int p = k & 1;
        const unsigned short* hA = h0ping + p * (32 * 1024) + (w * 16 + lr) * 1024 + kg * 8;
        f32x4 acc[4] = {};
#pragma unroll
        for (int kc = 0; kc < 32; kc++) {
          short8 a = *(const short8*)(hA + kc * 32);
#pragma unroll
          for (int g = 0; g < 4; g++) {
            const int rr = g * 16 + lr;
            short8 bf = *(const short8*)((const char*)lw + rr * 2048 +
                                         ((kc * 64 + kg * 16) ^ ((rr & 7) << 4)));
            acc[g] = __builtin_amdgcn_mfma_f32_16x16x32_bf16(a, bf, acc[g], 0, 0, 0);
          }
        }
        unsigned short* Hw = h0ping + (p ^ 1) * (32 * 1024);
#pragma unroll
        for (int r = 0; r < 4; r++) {
          const int b = w * 16 + kg * 4 + r;
          const unsigned short* Gr = G + (size_t)(k * 32 + b) * 4096 + j;
          const float gi = bf2f(Gr[0]) + acc[0][r];
          const float gf = bf2f(Gr[1024]) + acc[1][r];
          const float gg = bf2f(Gr[2048]) + acc[2][r];
          const float go = bf2f(Gr[3072]) + acc[3][r];
          const float cn = sig_(gf) * cc[r] + sig_(gi) * tanh_(gg);
          const float hn = sig_(go) * tanh_(cn);
          cc[r] = cn;
          Hw[b * 1024 + j] = f2bf(hn);
        }
      }
      if (k < 63) grid_bar(cnt, flag, 192, sense);
    }
  } else {
    // ---- dec1: jtile 8, rows r=jl*4+g (j-inner, gate-inner); LDS [32][2048] ----
    const int j0 = (bid - 64) * 8;
    for (int it = 0; it < 64; it++) {
      const int idx = (it * 128 + tid) * 16;
      const int r = idx >> 12, o = idx & 4095;
      const unsigned short* src =
          Wc1 + (size_t)((r & 3) * 1024 + j0 + (r >> 2)) * 2048 + (o >> 1);
      *(short8*)((char*)lw + r * 4096 + (o ^ ((r & 7) << 4))) = *(const short8*)src;
    }
    float cc[2][4];
    const int myg = lane & 3;
#pragma unroll
    for (int n = 0; n < 2; n++)
#pragma unroll
      for (int r = 0; r < 4; r++)
        cc[n][r] = c1init[(w * 16 + kg * 4 + r) * 1024 + (j0 + n * 4 + (lr >> 2))];
    __syncthreads();
    for (int k = 0; k < 64; k++) {
      if (k >= 1) {
        const int t = k - 1;
        const unsigned short* h0A =
            h0ping + (k & 1) * (32 * 1024) + (w * 16 + lr) * 1024 + kg * 8;
        const unsigned short* h1A =
            h1ping + ((k & 1) ^ 1) * (32 * 1024) + (w * 16 + lr) * 1024 + kg * 8;
        f32x4 acc[2] = {};
#pragma unroll
        for (int kc = 0; kc < 64; kc++) {
          short8 a = (kc < 32) ? *(const short8*)(h0A + kc * 32)
                               : *(const short8*)(h1A + (kc - 32) * 32);
#pragma unroll
          for (int n = 0; n < 2; n++) {
            const int rr = n * 16 + lr;
            short8 bf = *(const short8*)((const char*)lw + rr * 4096 +
                                         ((kc * 64 + kg * 16) ^ ((rr & 7) << 4)));
            acc[n] = __builtin_amdgcn_mfma_f32_16x16x32_bf16(a, bf, acc[n], 0, 0, 0);
          }
        }
        unsigned short* Hw = h1ping + (k & 1) * (32 * 1024);
#pragma unroll
        for (int n = 0; n < 2; n++) {
          const int j = j0 + n * 4 + (lr >> 2);
#pragma unroll
          for (int r = 0; r < 4; r++) {
            const int b = w * 16 + kg * 4 + r;
            // butterfly: 4-lane group holds gates i,f,g,o of same (b,j)
            const float v = acc[n][r];
            const float e1a = __shfl_xor(v, 1);
            const float e0 = (lane & 1) ? e1a : v;
            const float e1 = (lane & 1) ? v : e1a;
            const float f0 = __shfl_xor(e0, 2), f1 = __shfl_xor(e1, 2);
            const float gi = ((lane & 2) ? f0 : e0) + db1[j];
            const float gf = ((lane & 2) ? f1 : e1) + db1[1024 + j];
            const float gg = ((lane & 2) ? e0 : f0) + db1[2048 + j];
            const float go = ((lane & 2) ? e1 : f1) + db1[3072 + j];
            const float cn = sig_(gf) * cc[n][r] + sig_(gi) * tanh_(gg);
            const float hn = sig_(go) * tanh_(cn);
            cc[n][r] = cn;
            if (myg == 0) {
              const unsigned short hb = f2bf(hn);
              Hw[b * 1024 + j] = hb;
              H1all[(size_t)(t * 32 + b) * 1024 + j] = hb;
            }
          }
        }
      }
      if (k < 63) grid_bar(cnt, flag, 192, sense);
    }
  }
}

// ---------------------------------------------------------------------------
// Setup kernels
// ---------------------------------------------------------------------------
__global__ void cvt_bf16(const float* __restrict__ in, unsigned short* __restrict__ out,
                         long n4) {
  long i = (long)blockIdx.x * blockDim.x + threadIdx.x;
  const long stride = (long)gridDim.x * blockDim.x;
  for (; i < n4; i += stride) {
    f32x4 v = *(const f32x4*)&in[i * 4];
    ushort4 o = {f2bf(v.x), f2bf(v.y), f2bf(v.z), f2bf(v.w)};
    *(ushort4*)&out[i * 4] = o;
  }
}

__global__ void pack_wc1(const float* __restrict__ Wih1, const float* __restrict__ Whh1,
                         unsigned short* __restrict__ Wc) {
  const int n = blockIdx.x;
  const int c = threadIdx.x * 8;
  const float* src = (c < 1024) ? (Wih1 + (size_t)n * 1024 + c)
                                : (Whh1 + (size_t)n * 1024 + (c - 1024));
  f32x4 v0 = *(const f32x4*)src;
  f32x4 v1 = *(const f32x4*)(src + 4);
  ushort4 o0 = {f2bf(v0.x), f2bf(v0.y), f2bf(v0.z), f2bf(v0.w)};
  ushort4 o1 = {f2bf(v1.x), f2bf(v1.y), f2bf(v1.z), f2bf(v1.w)};
  *(ushort4*)&Wc[(size_t)n * 2048 + c] = o0;
  *(ushort4*)&Wc[(size_t)n * 2048 + c + 4] = o1;
}

__global__ void bias_comb(const float* __restrict__ a, const float* __restrict__ b,
                          float* __restrict__ out, int n) {
  int i = blockIdx.x * blockDim.x + threadIdx.x;
  if (i < n) out[i] = a[i] + b[i];
}

__global__ void embed_src(const int* __restrict__ x, const float* __restrict__ emb,
                          unsigned short* __restrict__ A0) {
  const int row = blockIdx.x;
  const int s = row >> 5, b = row & 31;
  const int tok = x[b * 64 + (63 - s)];
  const int col = threadIdx.x * 4;
  f32x4 v = *(const f32x4*)(emb + (size_t)tok * 1024 + col);
  ushort4 o = {f2bf(v.x), f2bf(v.y), f2bf(v.z), f2bf(v.w)};
  *(ushort4*)&A0[(size_t)row * 1024 + col] = o;
}

__global__ void embed_tgt(const int* __restrict__ y, const float* __restrict__ emb,
                          unsigned short* __restrict__ inp0) {
  const int row = blockIdx.x;
  const int col = threadIdx.x * 4;
  ushort4 o = {0, 0, 0, 0};
  if (row < 2016) {
    const int t = row >> 5, b = row & 31;
    const int tok = y[b * 64 + t];
    f32x4 v = *(const f32x4*)(emb + (size_t)tok * 1024 + col);
    o = ushort4{f2bf(v.x), f2bf(v.y), f2bf(v.z), f2bf(v.w)};
  } else {
    *(ushort4*)&inp0[(size_t)row * 2048 + 1024 + col] = o;
  }
  *(ushort4*)&inp0[(size_t)row * 2048 + col] = o;
}

__global__ void fill_ctx2(const unsigned short* __restrict__ Hl1,
                          unsigned short* __restrict__ inp0) {
  const int row = blockIdx.x;
  const int b = row & 31;
  const int col = threadIdx.x * 4;
  const int dir = col >> 9, jj = col & 511;
  ushort4 v = *(const ushort4*)(Hl1 + ((size_t)dir * 32 + b) * 512 + jj);
  *(ushort4*)&inp0[(size_t)row * 2048 + 1024 + col] = v;
}

__global__ void dec_init2(const unsigned short* __restrict__ Hl0,
                          const unsigned short* __restrict__ Hl1,
                          const float* __restrict__ Cl0, const float* __restrict__ Cl1,
                          unsigned short* __restrict__ H0, unsigned short* __restrict__ H1,
                          float* __restrict__ c0, float* __restrict__ c1) {
  const int i = blockIdx.x * 256 + threadIdx.x;
  const int b = i >> 10, col = i & 1023;
  const int dir = col >> 9, jj = col & 511;
  const int se = (dir * 32 + b) * 512 + jj;
  const int de = b * 1024 + col;
  H0[de] = Hl0[se];  // parity 0
  H1[de] = Hl1[se];  // parity 0
  c0[de] = Cl0[se];
  c1[de] = Cl1[se];
}

// ---------------------------------------------------------------------------
extern "C" void kernel_launch(void* const* d_in, const int* in_sizes, int n_in,
                              void* d_out, int out_size, void* d_ws, size_t ws_size,
                              hipStream_t stream) {
  const int* x = (const int*)d_in[0];
  const int* y = (const int*)d_in[1];
  const float* src_emb = (const float*)d_in[2];
  const float* tgt_emb = (const float*)d_in[3];
  const float* enc_W_ih = (const float*)d_in[4];
  const float* enc_W_hh = (const float*)d_in[5];
  const float* enc_b_ih = (const float*)d_in[6];
  const float* enc_b_hh = (const float*)d_in[7];
  const float* dec_W_ih0 = (const float*)d_in[8];
  const float* dec_W_ih1 = (const float*)d_in[9];
  const float* dec_W_hh = (const float*)d_in[10];
  const float* dec_b_ih = (const float*)d_in[11];
  const float* dec_b_hh = (const float*)d_in[12];
  const float* W_out = (const float*)d_in[13];
  const float* b_out = (const float*)d_in[14];
  float* out = (float*)d_out;

  char* ws = (char*)d_ws;
  size_t off = 0;
  auto alloc = [&](size_t bytes) -> void* {
    void* p = ws + off;
    off += (bytes + 255) & ~(size_t)255;
    return p;
  };
  unsigned short* A0 = (unsigned short*)alloc(2048ull * 1024 * 2);
  unsigned short* seq1 = (unsigned short*)alloc(2048ull * 1024 * 2);
  unsigned short* Wih_bf = (unsigned short*)alloc(2ull * 4096 * 1024 * 2);
  unsigned short* Wih0_bf = (unsigned short*)alloc(4096ull * 2048 * 2);
  unsigned short* Wout_bf = (unsigned short*)alloc(32000ull * 1024 * 2);
  unsigned short* G = (unsigned short*)alloc(2048ull * 4096 * 2);  // bf16 gates
  unsigned short* inp0 = (unsigned short*)alloc(2048ull * 2048 * 2);
  unsigned short* H1all = (unsigned short*)alloc(2048ull * 1024 * 2);
  unsigned short* Whh_enc_bf = (unsigned short*)alloc(2ull * 2 * 2048 * 512 * 2);
  unsigned short* Whh0_bf = (unsigned short*)alloc(4096ull * 1024 * 2);
  unsigned short* Wc1_bf = (unsigned short*)alloc(4096ull * 2048 * 2);
  float* encbias = (float*)alloc(2ull * 4096 * 4);
  float* decdb = (float*)alloc(2ull * 4096 * 4);
  // contiguous zero-init block: Hp_l0, Hp_l1
  unsigned short* Hp_l0 = (unsigned short*)alloc(2ull * 2 * 32 * 512 * 2);  // [p][d][b][j]
  unsigned short* Hp_l1 = (unsigned short*)alloc(2ull * 2 * 32 * 512 * 2);
  float* c_l0 = (float*)alloc(2ull * 32 * 512 * 4);  // [d][b][j] final enc c
  float* c_l1 = (float*)alloc(2ull * 32 * 512 * 4);
  unsigned short* H0pair = (unsigned short*)alloc(2ull * 32 * 1024 * 2);
  unsigned short* H1pair = (unsigned short*)alloc(2ull * 32 * 1024 * 2);
  float* c0buf = (float*)alloc(32ull * 1024 * 4);
  float* c1buf = (float*)alloc(32ull * 1024 * 4);
  int* bar = (int*)alloc(512);  // barrier pairs: (0,16) (32,48) (64,80)
  if (off > ws_size) return;

  hipFuncSetAttribute((const void*)enc_persist,
                      hipFuncAttributeMaxDynamicSharedMemorySize, 65536);
  hipFuncSetAttribute((const void*)dec_persist,
                      hipFuncAttributeMaxDynamicSharedMemorySize, 131072);

  // ---- setup ----
  cvt_bf16<<<1024, 256, 0, stream>>>(enc_W_ih, Wih_bf, (2ll * 4096 * 1024) / 4);
  cvt_bf16<<<1024, 256, 0, stream>>>(dec_W_ih0, Wih0_bf, (4096ll * 2048) / 4);
  cvt_bf16<<<2048, 256, 0, stream>>>(W_out, Wout_bf, (32000ll * 1024) / 4);
  cvt_bf16<<<1024, 256, 0, stream>>>(enc_W_hh, Whh_enc_bf, (2ll * 2 * 2048 * 512) / 4);
  cvt_bf16<<<1024, 256, 0, stream>>>(dec_W_hh, Whh0_bf, (4096ll * 1024) / 4);
  pack_wc1<<<4096, 256, 0, stream>>>(dec_W_ih1, dec_W_hh + 4096ll * 1024, Wc1_bf);
  bias_comb<<<32, 256, 0, stream>>>(enc_b_ih, enc_b_hh, encbias, 8192);
  bias_comb<<<32, 256, 0, stream>>>(dec_b_ih, dec_b_hh, decdb, 8192);
  embed_src<<<2048, 256, 0, stream>>>(x, src_emb, A0);
  embed_tgt<<<2048, 256, 0, stream>>>(y, tgt_emb, inp0);
  hipMemsetAsync(Hp_l0, 0, 2ull * (2 * 2 * 32 * 512) * 2, stream);  // Hp_l0 + Hp_l1
  hipMemsetAsync(H1all + 2016ull * 1024, 0, 32ull * 1024 * 2, stream);
  hipMemsetAsync(bar, 0, 512, stream);  // reset barriers EVERY call (replay-safe)

  // ---- encoder layer 0 ----
  gemm_bf16<<<dim3(32, 16), 256, 0, stream>>>(A0, Wih_bf, G, encbias, 1024, 4096, 2048, 2);
  enc_persist<<<64, 128, 65536, stream>>>(Whh_enc_bf, G, Hp_l0, seq1, c_l0, bar + 0, bar + 16);
  // ---- encoder layer 1 ----
  gemm_bf16<<<dim3(32, 16), 256, 0, stream>>>(seq1, Wih_bf + 4096ull * 1024, G,
                                              encbias + 4096, 1024, 4096, 2048, 2);
  enc_persist<<<64, 128, 65536, stream>>>(Whh_enc_bf + 2ull * 2048 * 512, G, Hp_l1, nullptr,
                                          c_l1, bar + 32, bar + 48);

  // ---- decoder setup ----
  dec_init2<<<128, 256, 0, stream>>>(Hp_l0, Hp_l1, c_l0, c_l1, H0pair, H1pair, c0buf, c1buf);
  fill_ctx2<<<2016, 256, 0, stream>>>(Hp_l1, inp0);
  gemm_bf16<<<dim3(32, 16), 256, 0, stream>>>(inp0, Wih0_bf, G, decdb, 2048, 4096, 2048, 2);

  // ---- decoder recurrence (persistent, software-pipelined) ----
  dec_persist<<<192, 128, 131072, stream>>>(Whh0_bf, Wc1_bf, G, decdb + 4096, c0buf, c1buf,
                                            H0pair, H1pair, H1all, bar + 64, bar + 80);

  // ---- logits ----
  gemm_bf16<<<dim3(250, 16), 256, 0, stream>>>(H1all, Wout_bf, out, b_out, 1024, 32000,
                                               2016, 1);
}

// Round 4
// 3376.361 us; speedup vs baseline: 3.1807x; 1.2755x over previous
//
#include <hip/hip_runtime.h>

typedef __attribute__((ext_vector_type(8))) short short8;
typedef __attribute__((ext_vector_type(4))) float f32x4;

#define DEVINL __device__ __forceinline__

DEVINL unsigned short f2bf(float f) {
  unsigned int u = __builtin_bit_cast(unsigned int, f);
  unsigned int r = u + 0x7FFFu + ((u >> 16) & 1u);  // RNE
  return (unsigned short)(r >> 16);
}
DEVINL float bf2f(unsigned short u) {
  unsigned int x = ((unsigned int)u) << 16;
  return __builtin_bit_cast(float, x);
}
DEVINL float sig_(float x) { return 1.f / (1.f + __expf(-x)); }
DEVINL float tanh_(float x) { return 2.f / (1.f + __expf(-2.f * x)) - 1.f; }

DEVINL void gld16(void* lds, const void* g) {
  __builtin_amdgcn_global_load_lds(
      (const __attribute__((address_space(1))) unsigned int*)g,
      (__attribute__((address_space(3))) unsigned int*)lds, 16, 0, 0);
}

// ---- grid barrier: RELAXED poll (no per-poll L2 inv), fences only at edges --
DEVINL void grid_bar(int* cnt, int* flag, int nb, int& sense) {
  __syncthreads();  // drains vmcnt -> stores in L2
  if (threadIdx.x == 0) {
    sense ^= 1;
    __builtin_amdgcn_fence(__ATOMIC_RELEASE, "agent");  // wb L2 once
    if (__hip_atomic_fetch_add(cnt, 1, __ATOMIC_ACQ_REL, __HIP_MEMORY_SCOPE_AGENT) == nb - 1) {
      __hip_atomic_store(cnt, 0, __ATOMIC_RELAXED, __HIP_MEMORY_SCOPE_AGENT);
      __hip_atomic_store(flag, sense, __ATOMIC_RELEASE, __HIP_MEMORY_SCOPE_AGENT);
    } else {
      while (__hip_atomic_load(flag, __ATOMIC_RELAXED, __HIP_MEMORY_SCOPE_AGENT) != sense)
        __builtin_amdgcn_s_sleep(4);
    }
    __builtin_amdgcn_fence(__ATOMIC_ACQUIRE, "agent");  // inv once
  }
  __syncthreads();
}

// ---------------------------------------------------------------------------
// bf16 GEMM: C[M,N] = A[M,K] @ Bt[N,K]^T + bias[N]
// mode 0: f32 C. mode 1: logits scatter f32. mode 2: bf16 C.
// ---------------------------------------------------------------------------
__global__ __launch_bounds__(256) void gemm_bf16(
    const unsigned short* __restrict__ A, const unsigned short* __restrict__ Bt,
    void* __restrict__ C, const float* __restrict__ bias,
    int K, int N, int Mvalid, int mode) {
  __shared__ unsigned short lA[512 * 8];
  __shared__ unsigned short lB[512 * 8];
  const int tid = threadIdx.x;
  const int lane = tid & 63, wid = tid >> 6;
  const int wm = wid >> 1, wn = wid & 1;
  const int bn = blockIdx.x, bm = blockIdx.y;
  const size_t K_ = (size_t)K;

  const int s0 = tid, s1 = tid + 256;
  const int r0 = s0 & 127, kb0 = s0 >> 7;
  const int r1 = s1 & 127, kb1 = s1 >> 7;
  const unsigned short* gA0 = A + (size_t)(bm * 128 + r0) * K_ + kb0 * 8;
  const unsigned short* gA1 = A + (size_t)(bm * 128 + r1) * K_ + kb1 * 8;
  const unsigned short* gB0 = Bt + (size_t)(bn * 128 + r0) * K_ + kb0 * 8;
  const unsigned short* gB1 = Bt + (size_t)(bn * 128 + r1) * K_ + kb1 * 8;
  unsigned short* lA0 = lA + (size_t)(wid * 64) * 8;
  unsigned short* lA1 = lA + (size_t)(256 + wid * 64) * 8;
  unsigned short* lB0 = lB + (size_t)(wid * 64) * 8;
  unsigned short* lB1 = lB + (size_t)(256 + wid * 64) * 8;

  f32x4 acc[4][4] = {};
  const int kg = lane >> 4, lr = lane & 15;

  for (int kt = 0; kt < K; kt += 32) {
    gld16(lA0, gA0 + kt);
    gld16(lA1, gA1 + kt);
    gld16(lB0, gB0 + kt);
    gld16(lB1, gB1 + kt);
    __syncthreads();
    short8 af[4], bfr[4];
#pragma unroll
    for (int fm = 0; fm < 4; fm++)
      af[fm] = *(const short8*)&lA[(size_t)(kg * 128 + wm * 64 + fm * 16 + lr) * 8];
#pragma unroll
    for (int fn = 0; fn < 4; fn++)
      bfr[fn] = *(const short8*)&lB[(size_t)(kg * 128 + wn * 64 + fn * 16 + lr) * 8];
#pragma unroll
    for (int fm = 0; fm < 4; fm++)
#pragma unroll
      for (int fn = 0; fn < 4; fn++)
        acc[fm][fn] =
            __builtin_amdgcn_mfma_f32_16x16x32_bf16(af[fm], bfr[fn], acc[fm][fn], 0, 0, 0);
    __syncthreads();
  }

#pragma unroll
  for (int fn = 0; fn < 4; fn++) {
    const int col = bn * 128 + wn * 64 + fn * 16 + lr;
    const float bv = bias ? bias[col] : 0.f;
#pragma unroll
    for (int fm = 0; fm < 4; fm++) {
      const int row0 = bm * 128 + wm * 64 + fm * 16 + kg * 4;
#pragma unroll
      for (int r = 0; r < 4; r++) {
        const int m = row0 + r;
        if (m < Mvalid) {
          const float v = acc[fm][fn][r] + bv;
          if (mode == 0) {
            ((float*)C)[(size_t)m * N + col] = v;
          } else if (mode == 1) {
            const int b = m & 31, t = m >> 5;
            ((float*)C)[(size_t)b * 2016000 + (size_t)t * 32000 + col] = v;
          } else {
            ((unsigned short*)C)[(size_t)m * N + col] = f2bf(v);
          }
        }
      }
    }
  }
}

// ---------------------------------------------------------------------------
// Encoder chain: grid 32 (dir*16 + jtile32), block 128, 128KB dyn LDS.
// LDS row rr (0..127) = W row (rr>>5)*512 + j0 + (rr&31), XOR-swizzled.
// Barrier group = 16 blocks per direction (independent pairs).
// ---------------------------------------------------------------------------
__global__ __launch_bounds__(128, 1) void enc_chain(
    const unsigned short* __restrict__ Whh, const unsigned short* __restrict__ G,
    unsigned short* __restrict__ Hping, unsigned short* __restrict__ seq_out,
    float* __restrict__ c_out, int* bar) {
  extern __shared__ unsigned short lw[];
  const int tid = threadIdx.x, lane = tid & 63, w = tid >> 6;
  const int lr = lane & 15, kg = lane >> 4;
  const int dir = (int)blockIdx.x >> 4, j0 = ((int)blockIdx.x & 15) * 32;
  int* cnt = bar + dir * 32;
  int* flag = bar + dir * 32 + 16;
  const unsigned short* Wd = Whh + (size_t)dir * 2048 * 512;
  for (int it = 0; it < 64; it++) {
    const int idx = (it * 128 + tid) * 16;
    const int r = idx >> 10, o = idx & 1023;
    const unsigned short* src = Wd + (size_t)((r >> 5) * 512 + j0 + (r & 31)) * 512 + (o >> 1);
    *(short8*)((char*)lw + r * 1024 + (o ^ ((r & 7) << 4))) = *(const short8*)src;
  }
  float cc[2][4] = {};
  int sense = 0;
  __syncthreads();
  for (int t = 0; t < 64; t++) {
    const int p = t & 1;
    const int s_idx = dir ? (63 - t) : t;
    const unsigned short* hA =
        Hping + ((size_t)p * 2 + dir) * (32 * 512) + (w * 16 + lr) * 512 + kg * 8;
    short8 areg[16];
#pragma unroll
    for (int kc = 0; kc < 16; kc++) areg[kc] = *(const short8*)(hA + kc * 32);
    float gpre[4][2][4];  // [r][jh][gate]
#pragma unroll
    for (int r = 0; r < 4; r++) {
      const unsigned short* Gr =
          G + (size_t)(s_idx * 32 + (w * 16 + kg * 4 + r)) * 4096 + dir * 2048;
#pragma unroll
      for (int jh = 0; jh < 2; jh++) {
        const int jj = j0 + jh * 16 + lr;
        gpre[r][jh][0] = bf2f(Gr[jj]);
        gpre[r][jh][1] = bf2f(Gr[512 + jj]);
        gpre[r][jh][2] = bf2f(Gr[1024 + jj]);
        gpre[r][jh][3] = bf2f(Gr[1536 + jj]);
      }
    }
    f32x4 acc[8] = {};
#pragma unroll
    for (int kc = 0; kc < 16; kc++) {
#pragma unroll
      for (int nt = 0; nt < 8; nt++) {
        const int rr = nt * 16 + lr;
        short8 bf = *(const short8*)((const char*)lw + rr * 1024 +
                                     ((kc * 64 + kg * 16) ^ ((rr & 7) << 4)));
        acc[nt] = __builtin_amdgcn_mfma_f32_16x16x32_bf16(areg[kc], bf, acc[nt], 0, 0, 0);
      }
    }
    unsigned short* Hw = Hping + ((size_t)(p ^ 1) * 2 + dir) * (32 * 512);
#pragma unroll
    for (int r = 0; r < 4; r++) {
      const int b = w * 16 + kg * 4 + r;
#pragma unroll
      for (int jh = 0; jh < 2; jh++) {
        const int jj = j0 + jh * 16 + lr;
        const float gi = gpre[r][jh][0] + acc[jh + 0][r];
        const float gf = gpre[r][jh][1] + acc[jh + 2][r];
        const float gg = gpre[r][jh][2] + acc[jh + 4][r];
        const float go = gpre[r][jh][3] + acc[jh + 6][r];
        const float cn = sig_(gf) * cc[jh][r] + sig_(gi) * tanh_(gg);
        const float hn = sig_(go) * tanh_(cn);
        cc[jh][r] = cn;
        const unsigned short hb = f2bf(hn);
        Hw[b * 512 + jj] = hb;
        if (seq_out) seq_out[(size_t)(s_idx * 32 + b) * 1024 + dir * 512 + jj] = hb;
      }
    }
    if (t < 63) grid_bar(cnt, flag, 16, sense);
  }
#pragma unroll
  for (int r = 0; r < 4; r++)
#pragma unroll
    for (int jh = 0; jh < 2; jh++)
      c_out[(dir * 32 + (w * 16 + kg * 4 + r)) * 512 + j0 + jh * 16 + lr] = cc[jh][r];
}

// ---------------------------------------------------------------------------
// Decoder chain (used for both cells; h1 never feeds cell0, so cells run as
// two sequential chains with a batch GEMM between). grid 64 (jtile16),
// block 128, 128KB dyn LDS. Hext rows (t+1)*32+b; rows 0..31 = init state.
// ---------------------------------------------------------------------------
__global__ __launch_bounds__(128, 1) void dec_chain(
    const unsigned short* __restrict__ W, const unsigned short* __restrict__ G,
    const float* __restrict__ cinit, unsigned short* __restrict__ Hext,
    int* cnt, int* flag) {
  extern __shared__ unsigned short lw[];
  const int tid = threadIdx.x, lane = tid & 63, w = tid >> 6;
  const int lr = lane & 15, kg = lane >> 4;
  const int j0 = (int)blockIdx.x * 16, j = j0 + lr;
  for (int it = 0; it < 64; it++) {
    const int idx = (it * 128 + tid) * 16;
    const int r = idx >> 11, o = idx & 2047;
    const unsigned short* src = W + (size_t)((r >> 4) * 1024 + j0 + (r & 15)) * 1024 + (o >> 1);
    *(short8*)((char*)lw + r * 2048 + (o ^ ((r & 7) << 4))) = *(const short8*)src;
  }
  float cc[4];
#pragma unroll
  for (int r = 0; r < 4; r++) cc[r] = cinit[(w * 16 + kg * 4 + r) * 1024 + j];
  int sense = 0;
  __syncthreads();
  for (int k = 0; k < 63; k++) {
    const unsigned short* hA = Hext + (size_t)k * 32 * 1024 + (w * 16 + lr) * 1024 + kg * 8;
    short8 areg[32];
#pragma unroll
    for (int kc = 0; kc < 32; kc++) areg[kc] = *(const short8*)(hA + kc * 32);
    float gpre[4][4];  // [r][gate]
#pragma unroll
    for (int r = 0; r < 4; r++) {
      const unsigned short* Gr = G + (size_t)(k * 32 + (w * 16 + kg * 4 + r)) * 4096 + j;
      gpre[r][0] = bf2f(Gr[0]);
      gpre[r][1] = bf2f(Gr[1024]);
      gpre[r][2] = bf2f(Gr[2048]);
      gpre[r][3] = bf2f(Gr[3072]);
    }
    f32x4 acc[4] = {};
#pragma unroll
    for (int kc = 0; kc < 32; kc++) {
#pragma unroll
      for (int g = 0; g < 4; g++) {
        const int rr = g * 16 + lr;
        short8 bf = *(const short8*)((const char*)lw + rr * 2048 +
                                     ((kc * 64 + kg * 16) ^ ((rr & 7) << 4)));
        acc[g] = __builtin_amdgcn_mfma_f32_16x16x32_bf16(areg[kc], bf, acc[g], 0, 0, 0);
      }
    }
    unsigned short* Hw = Hext + (size_t)(k + 1) * 32 * 1024;
#pragma unroll
    for (int r = 0; r < 4; r++) {
      const int b = w * 16 + kg * 4 + r;
      const float gi = gpre[r][0] + acc[0][r];
      const float gf = gpre[r][1] + acc[1][r];
      const float gg = gpre[r][2] + acc[2][r];
      const float go = gpre[r][3] + acc[3][r];
      const float cn = sig_(gf) * cc[r] + sig_(gi) * tanh_(gg);
      const float hn = sig_(go) * tanh_(cn);
      cc[r] = cn;
      Hw[b * 1024 + j] = f2bf(hn);
    }
    if (k < 62) grid_bar(cnt, flag, 64, sense);
  }
}

// ---------------------------------------------------------------------------
// Setup kernels
// ---------------------------------------------------------------------------
__global__ void cvt_bf16(const float* __restrict__ in, unsigned short* __restrict__ out,
                         long n4) {
  long i = (long)blockIdx.x * blockDim.x + threadIdx.x;
  const long stride = (long)gridDim.x * blockDim.x;
  for (; i < n4; i += stride) {
    f32x4 v = *(const f32x4*)&in[i * 4];
    ushort4 o = {f2bf(v.x), f2bf(v.y), f2bf(v.z), f2bf(v.w)};
    *(ushort4*)&out[i * 4] = o;
  }
}

__global__ void bias_comb(const float* __restrict__ a, const float* __restrict__ b,
                          float* __restrict__ out, int n) {
  int i = blockIdx.x * blockDim.x + threadIdx.x;
  if (i < n) out[i] = a[i] + b[i];
}

__global__ void embed_src(const int* __restrict__ x, const float* __restrict__ emb,
                          unsigned short* __restrict__ A0) {
  const int row = blockIdx.x;
  const int s = row >> 5, b = row & 31;
  const int tok = x[b * 64 + (63 - s)];
  const int col = threadIdx.x * 4;
  f32x4 v = *(const f32x4*)(emb + (size_t)tok * 1024 + col);
  ushort4 o = {f2bf(v.x), f2bf(v.y), f2bf(v.z), f2bf(v.w)};
  *(ushort4*)&A0[(size_t)row * 1024 + col] = o;
}

__global__ void embed_tgt(const int* __restrict__ y, const float* __restrict__ emb,
                          unsigned short* __restrict__ inp0) {
  const int row = blockIdx.x;
  const int col = threadIdx.x * 4;
  ushort4 o = {0, 0, 0, 0};
  if (row < 2016) {
    const int t = row >> 5, b = row & 31;
    const int tok = y[b * 64 + t];
    f32x4 v = *(const f32x4*)(emb + (size_t)tok * 1024 + col);
    o = ushort4{f2bf(v.x), f2bf(v.y), f2bf(v.z), f2bf(v.w)};
  } else {
    *(ushort4*)&inp0[(size_t)row * 2048 + 1024 + col] = o;
  }
  *(ushort4*)&inp0[(size_t)row * 2048 + col] = o;
}

__global__ void fill_ctx2(const unsigned short* __restrict__ Hl1,
                          unsigned short* __restrict__ inp0) {
  const int row = blockIdx.x;
  const int b = row & 31;
  const int col = threadIdx.x * 4;
  const int dir = col >> 9, jj = col & 511;
  ushort4 v = *(const ushort4*)(Hl1 + ((size_t)dir * 32 + b) * 512 + jj);
  *(ushort4*)&inp0[(size_t)row * 2048 + 1024 + col] = v;
}

// init rows 0..31 of H0ext/H1ext + c bufs from encoder finals; grid 128 x 256
__global__ void dec_init2(const unsigned short* __restrict__ Hl0,
                          const unsigned short* __restrict__ Hl1,
                          const float* __restrict__ Cl0, const float* __restrict__ Cl1,
                          unsigned short* __restrict__ H0e, unsigned short* __restrict__ H1e,
                          float* __restrict__ c0, float* __restrict__ c1) {
  const int i = blockIdx.x * 256 + threadIdx.x;
  const int b = i >> 10, col = i & 1023;
  const int dir = col >> 9, jj = col & 511;
  const int se = (dir * 32 + b) * 512 + jj;
  const int de = b * 1024 + col;
  H0e[de] = Hl0[se];
  H1e[de] = Hl1[se];
  c0[de] = Cl0[se];
  c1[de] = Cl1[se];
}

// ---------------------------------------------------------------------------
extern "C" void kernel_launch(void* const* d_in, const int* in_sizes, int n_in,
                              void* d_out, int out_size, void* d_ws, size_t ws_size,
                              hipStream_t stream) {
  const int* x = (const int*)d_in[0];
  const int* y = (const int*)d_in[1];
  const float* src_emb = (const float*)d_in[2];
  const float* tgt_emb = (const float*)d_in[3];
  const float* enc_W_ih = (const float*)d_in[4];
  const float* enc_W_hh = (const float*)d_in[5];
  const float* enc_b_ih = (const float*)d_in[6];
  const float* enc_b_hh = (const float*)d_in[7];
  const float* dec_W_ih0 = (const float*)d_in[8];
  const float* dec_W_ih1 = (const float*)d_in[9];
  const float* dec_W_hh = (const float*)d_in[10];
  const float* dec_b_ih = (const float*)d_in[11];
  const float* dec_b_hh = (const float*)d_in[12];
  const float* W_out = (const float*)d_in[13];
  const float* b_out = (const float*)d_in[14];
  float* out = (float*)d_out;

  char* ws = (char*)d_ws;
  size_t off = 0;
  auto alloc = [&](size_t bytes) -> void* {
    void* p = ws + off;
    off += (bytes + 255) & ~(size_t)255;
    return p;
  };
  unsigned short* A0 = (unsigned short*)alloc(2048ull * 1024 * 2);
  unsigned short* seq1 = (unsigned short*)alloc(2048ull * 1024 * 2);
  unsigned short* Wih_bf = (unsigned short*)alloc(2ull * 4096 * 1024 * 2);
  unsigned short* Wih0_bf = (unsigned short*)alloc(4096ull * 2048 * 2);
  unsigned short* Wih1_bf = (unsigned short*)alloc(4096ull * 1024 * 2);
  unsigned short* Wout_bf = (unsigned short*)alloc(32000ull * 1024 * 2);
  unsigned short* G = (unsigned short*)alloc(2048ull * 4096 * 2);  // bf16 gates (reused)
  unsigned short* inp0 = (unsigned short*)alloc(2048ull * 2048 * 2);
  unsigned short* Whh_enc_bf = (unsigned short*)alloc(2ull * 2 * 2048 * 512 * 2);
  unsigned short* Whh0_bf = (unsigned short*)alloc(4096ull * 1024 * 2);
  unsigned short* Whh1_bf = (unsigned short*)alloc(4096ull * 1024 * 2);
  unsigned short* H0ext = (unsigned short*)alloc(2080ull * 1024 * 2);  // row0-31=init
  unsigned short* H1ext = (unsigned short*)alloc(2080ull * 1024 * 2);
  float* encbias = (float*)alloc(2ull * 4096 * 4);
  float* decdb = (float*)alloc(2ull * 4096 * 4);
  unsigned short* Hp_l0 = (unsigned short*)alloc(2ull * 2 * 32 * 512 * 2);  // [p][d][b][j]
  unsigned short* Hp_l1 = (unsigned short*)alloc(2ull * 2 * 32 * 512 * 2);
  float* c_l0 = (float*)alloc(2ull * 32 * 512 * 4);
  float* c_l1 = (float*)alloc(2ull * 32 * 512 * 4);
  float* c0buf = (float*)alloc(32ull * 1024 * 4);
  float* c1buf = (float*)alloc(32ull * 1024 * 4);
  int* bar = (int*)alloc(256 * 4);  // 6 pairs at 32-int stride
  if (off > ws_size) return;

  hipFuncSetAttribute((const void*)enc_chain,
                      hipFuncAttributeMaxDynamicSharedMemorySize, 131072);
  hipFuncSetAttribute((const void*)dec_chain,
                      hipFuncAttributeMaxDynamicSharedMemorySize, 131072);

  // ---- setup ----
  cvt_bf16<<<1024, 256, 0, stream>>>(enc_W_ih, Wih_bf, (2ll * 4096 * 1024) / 4);
  cvt_bf16<<<1024, 256, 0, stream>>>(dec_W_ih0, Wih0_bf, (4096ll * 2048) / 4);
  cvt_bf16<<<1024, 256, 0, stream>>>(dec_W_ih1, Wih1_bf, (4096ll * 1024) / 4);
  cvt_bf16<<<2048, 256, 0, stream>>>(W_out, Wout_bf, (32000ll * 1024) / 4);
  cvt_bf16<<<1024, 256, 0, stream>>>(enc_W_hh, Whh_enc_bf, (2ll * 2 * 2048 * 512) / 4);
  cvt_bf16<<<1024, 256, 0, stream>>>(dec_W_hh, Whh0_bf, (4096ll * 1024) / 4);
  cvt_bf16<<<1024, 256, 0, stream>>>(dec_W_hh + 4096ll * 1024, Whh1_bf, (4096ll * 1024) / 4);
  bias_comb<<<32, 256, 0, stream>>>(enc_b_ih, enc_b_hh, encbias, 8192);
  bias_comb<<<32, 256, 0, stream>>>(dec_b_ih, dec_b_hh, decdb, 8192);
  embed_src<<<2048, 256, 0, stream>>>(x, src_emb, A0);
  embed_tgt<<<2048, 256, 0, stream>>>(y, tgt_emb, inp0);
  hipMemsetAsync(Hp_l0, 0, 2ull * (2 * 2 * 32 * 512) * 2, stream);  // Hp_l0 + Hp_l1
  hipMemsetAsync(bar, 0, 256 * 4, stream);  // reset barriers EVERY call (replay-safe)

  // ---- encoder layer 0 ----
  gemm_bf16<<<dim3(32, 16), 256, 0, stream>>>(A0, Wih_bf, G, encbias, 1024, 4096, 2048, 2);
  enc_chain<<<32, 128, 131072, stream>>>(Whh_enc_bf, G, Hp_l0, seq1, c_l0, bar + 0);
  // ---- encoder layer 1 ----
  gemm_bf16<<<dim3(32, 16), 256, 0, stream>>>(seq1, Wih_bf + 4096ull * 1024, G,
                                              encbias + 4096, 1024, 4096, 2048, 2);
  enc_chain<<<32, 128, 131072, stream>>>(Whh_enc_bf + 2ull * 2048 * 512, G, Hp_l1, nullptr,
                                         c_l1, bar + 64);

  // ---- decoder setup ----
  dec_init2<<<128, 256, 0, stream>>>(Hp_l0, Hp_l1, c_l0, c_l1, H0ext, H1ext, c0buf, c1buf);
  fill_ctx2<<<2016, 256, 0, stream>>>(Hp_l1, inp0);
  gemm_bf16<<<dim3(32, 16), 256, 0, stream>>>(inp0, Wih0_bf, G, decdb, 2048, 4096, 2048, 2);

  // ---- decoder cell0 chain ----
  dec_chain<<<64, 128, 131072, stream>>>(Whh0_bf, G, c0buf, H0ext, bar + 128, bar + 144);
  // ---- G1 = H0seq @ Wih1^T + db1 (batch GEMM replaces per-step K=2048 half) ----
  gemm_bf16<<<dim3(32, 16), 256, 0, stream>>>(H0ext + 32ull * 1024, Wih1_bf, G,
                                              decdb + 4096, 1024, 4096, 2016, 2);
  // ---- decoder cell1 chain ----
  dec_chain<<<64, 128, 131072, stream>>>(Whh1_bf, G, c1buf, H1ext, bar + 160, bar + 176);

  // ---- logits ----
  gemm_bf16<<<dim3(250, 16), 256, 0, stream>>>(H1ext + 32ull * 1024, Wout_bf, out, b_out,
                                               1024, 32000, 2016, 1);
}

// Round 5
// 2774.020 us; speedup vs baseline: 3.8714x; 1.2171x over previous
//
#include <hip/hip_runtime.h>

typedef __attribute__((ext_vector_type(8))) short short8;
typedef __attribute__((ext_vector_type(4))) float f32x4;

#define DEVINL __device__ __forceinline__

DEVINL unsigned short f2bf(float f) {
  unsigned int u = __builtin_bit_cast(unsigned int, f);
  unsigned int r = u + 0x7FFFu + ((u >> 16) & 1u);  // RNE
  return (unsigned short)(r >> 16);
}
DEVINL float bf2f(unsigned short u) {
  unsigned int x = ((unsigned int)u) << 16;
  return __builtin_bit_cast(float, x);
}
DEVINL float sig_(float x) { return 1.f / (1.f + __expf(-x)); }
DEVINL float tanh_(float x) { return 2.f / (1.f + __expf(-2.f * x)) - 1.f; }

DEVINL void gld16(void* lds, const void* g) {
  __builtin_amdgcn_global_load_lds(
      (const __attribute__((address_space(1))) unsigned int*)g,
      (__attribute__((address_space(3))) unsigned int*)lds, 16, 0, 0);
}

// ---- coherent 8B exchange: agent-scope relaxed atomics bypass L1/L2 --------
DEVINL unsigned long long coh_ld(const unsigned long long* p) {
  return __hip_atomic_load(p, __ATOMIC_RELAXED, __HIP_MEMORY_SCOPE_AGENT);
}
DEVINL void coh_st(unsigned long long* p, unsigned long long v) {
  __hip_atomic_store(p, v, __ATOMIC_RELAXED, __HIP_MEMORY_SCOPE_AGENT);
}
struct u64x2 {
  unsigned long long x, y;
};
DEVINL short8 mk8(unsigned long long a, unsigned long long b) {
  u64x2 t{a, b};
  return __builtin_bit_cast(short8, t);
}

// ---- fence-free grid barrier: relaxed add + relaxed poll, no cache maint ---
// Safe because ALL cross-block data moves via coh_ld/coh_st (coherence point);
// __syncthreads drains each wave's vmcnt (stores globally visible) pre-arrive.
DEVINL void grid_bar(int* cnt, int* flag, int nb, int& sense) {
  __syncthreads();
  if (threadIdx.x == 0) {
    sense ^= 1;
    if (__hip_atomic_fetch_add(cnt, 1, __ATOMIC_RELAXED, __HIP_MEMORY_SCOPE_AGENT) == nb - 1) {
      __hip_atomic_store(cnt, 0, __ATOMIC_RELAXED, __HIP_MEMORY_SCOPE_AGENT);
      __hip_atomic_store(flag, sense, __ATOMIC_RELAXED, __HIP_MEMORY_SCOPE_AGENT);
    } else {
      while (__hip_atomic_load(flag, __ATOMIC_RELAXED, __HIP_MEMORY_SCOPE_AGENT) != sense)
        __builtin_amdgcn_s_sleep(2);
    }
  }
  __syncthreads();
}

// ---------------------------------------------------------------------------
// bf16 GEMM: C[M,N] = A[M,K] @ Bt[N,K]^T + bias[N]
// mode 0: f32 C. mode 1: logits scatter f32. mode 2: bf16 C.
// ---------------------------------------------------------------------------
__global__ __launch_bounds__(256) void gemm_bf16(
    const unsigned short* __restrict__ A, const unsigned short* __restrict__ Bt,
    void* __restrict__ C, const float* __restrict__ bias,
    int K, int N, int Mvalid, int mode) {
  __shared__ unsigned short lA[512 * 8];
  __shared__ unsigned short lB[512 * 8];
  const int tid = threadIdx.x;
  const int lane = tid & 63, wid = tid >> 6;
  const int wm = wid >> 1, wn = wid & 1;
  const int bn = blockIdx.x, bm = blockIdx.y;
  const size_t K_ = (size_t)K;

  const int s0 = tid, s1 = tid + 256;
  const int r0 = s0 & 127, kb0 = s0 >> 7;
  const int r1 = s1 & 127, kb1 = s1 >> 7;
  const unsigned short* gA0 = A + (size_t)(bm * 128 + r0) * K_ + kb0 * 8;
  const unsigned short* gA1 = A + (size_t)(bm * 128 + r1) * K_ + kb1 * 8;
  const unsigned short* gB0 = Bt + (size_t)(bn * 128 + r0) * K_ + kb0 * 8;
  const unsigned short* gB1 = Bt + (size_t)(bn * 128 + r1) * K_ + kb1 * 8;
  unsigned short* lA0 = lA + (size_t)(wid * 64) * 8;
  unsigned short* lA1 = lA + (size_t)(256 + wid * 64) * 8;
  unsigned short* lB0 = lB + (size_t)(wid * 64) * 8;
  unsigned short* lB1 = lB + (size_t)(256 + wid * 64) * 8;

  f32x4 acc[4][4] = {};
  const int kg = lane >> 4, lr = lane & 15;

  for (int kt = 0; kt < K; kt += 32) {
    gld16(lA0, gA0 + kt);
    gld16(lA1, gA1 + kt);
    gld16(lB0, gB0 + kt);
    gld16(lB1, gB1 + kt);
    __syncthreads();
    short8 af[4], bfr[4];
#pragma unroll
    for (int fm = 0; fm < 4; fm++)
      af[fm] = *(const short8*)&lA[(size_t)(kg * 128 + wm * 64 + fm * 16 + lr) * 8];
#pragma unroll
    for (int fn = 0; fn < 4; fn++)
      bfr[fn] = *(const short8*)&lB[(size_t)(kg * 128 + wn * 64 + fn * 16 + lr) * 8];
#pragma unroll
    for (int fm = 0; fm < 4; fm++)
#pragma unroll
      for (int fn = 0; fn < 4; fn++)
        acc[fm][fn] =
            __builtin_amdgcn_mfma_f32_16x16x32_bf16(af[fm], bfr[fn], acc[fm][fn], 0, 0, 0);
    __syncthreads();
  }

#pragma unroll
  for (int fn = 0; fn < 4; fn++) {
    const int col = bn * 128 + wn * 64 + fn * 16 + lr;
    const float bv = bias ? bias[col] : 0.f;
#pragma unroll
    for (int fm = 0; fm < 4; fm++) {
      const int row0 = bm * 128 + wm * 64 + fm * 16 + kg * 4;
#pragma unroll
      for (int r = 0; r < 4; r++) {
        const int m = row0 + r;
        if (m < Mvalid) {
          const float v = acc[fm][fn][r] + bv;
          if (mode == 0) {
            ((float*)C)[(size_t)m * N + col] = v;
          } else if (mode == 1) {
            const int b = m & 31, t = m >> 5;
            ((float*)C)[(size_t)b * 2016000 + (size_t)t * 32000 + col] = v;
          } else {
            ((unsigned short*)C)[(size_t)m * N + col] = f2bf(v);
          }
        }
      }
    }
  }
}

// ---------------------------------------------------------------------------
// Encoder chain: grid 32 (dir*16 + jtile32), block 128, 128KB dyn LDS.
// h exchange via coherent 8B atomics; gpre(t+1) prefetched before barrier.
// ---------------------------------------------------------------------------
__global__ __launch_bounds__(128, 1) void enc_chain(
    const unsigned short* __restrict__ Whh, const unsigned short* __restrict__ G,
    unsigned short* __restrict__ Hping, unsigned short* __restrict__ seq_out,
    float* __restrict__ c_out, int* bar) {
  extern __shared__ unsigned short lw[];
  __shared__ unsigned short ht[32][36];  // 72B rows: pad for bank spread
  const int tid = threadIdx.x, lane = tid & 63, w = tid >> 6;
  const int lr = lane & 15, kg = lane >> 4;
  const int dir = (int)blockIdx.x >> 4, j0 = ((int)blockIdx.x & 15) * 32;
  int* cnt = bar + dir * 32;
  int* flag = bar + dir * 32 + 16;
  const unsigned short* Wd = Whh + (size_t)dir * 2048 * 512;
  for (int it = 0; it < 64; it++) {
    const int idx = (it * 128 + tid) * 16;
    const int r = idx >> 10, o = idx & 1023;
    const unsigned short* src = Wd + (size_t)((r >> 5) * 512 + j0 + (r & 31)) * 512 + (o >> 1);
    *(short8*)((char*)lw + r * 1024 + (o ^ ((r & 7) << 4))) = *(const short8*)src;
  }
  float cc[2][4] = {};
  int sense = 0;
  float gpre[4][2][4];
  auto fetch_g = [&](int t) {
    const int s_idx = dir ? (63 - t) : t;
#pragma unroll
    for (int r = 0; r < 4; r++) {
      const unsigned short* Gr =
          G + (size_t)(s_idx * 32 + (w * 16 + kg * 4 + r)) * 4096 + dir * 2048;
#pragma unroll
      for (int jh = 0; jh < 2; jh++) {
        const int jj = j0 + jh * 16 + lr;
        gpre[r][jh][0] = bf2f(Gr[jj]);
        gpre[r][jh][1] = bf2f(Gr[512 + jj]);
        gpre[r][jh][2] = bf2f(Gr[1024 + jj]);
        gpre[r][jh][3] = bf2f(Gr[1536 + jj]);
      }
    }
  };
  fetch_g(0);
  __syncthreads();
  const unsigned long long* HU = (const unsigned long long*)Hping;
  for (int t = 0; t < 64; t++) {
    const int p = t & 1;
    const int rowb = ((p * 2 + dir) * 32 + w * 16 + lr) * 128 + kg * 2;
    short8 areg[16];
#pragma unroll
    for (int kc = 0; kc < 16; kc++)
      areg[kc] = mk8(coh_ld(HU + rowb + kc * 8), coh_ld(HU + rowb + kc * 8 + 1));
    f32x4 acc[8] = {};
#pragma unroll
    for (int kc = 0; kc < 16; kc++)
#pragma unroll
      for (int nt = 0; nt < 8; nt++) {
        const int rr = nt * 16 + lr;
        short8 bf = *(const short8*)((const char*)lw + rr * 1024 +
                                     ((kc * 64 + kg * 16) ^ ((rr & 7) << 4)));
        acc[nt] = __builtin_amdgcn_mfma_f32_16x16x32_bf16(areg[kc], bf, acc[nt], 0, 0, 0);
      }
    const int s_idx = dir ? (63 - t) : t;
#pragma unroll
    for (int r = 0; r < 4; r++) {
      const int b = w * 16 + kg * 4 + r;
#pragma unroll
      for (int jh = 0; jh < 2; jh++) {
        const int jj = j0 + jh * 16 + lr;
        const float gi = gpre[r][jh][0] + acc[jh + 0][r];
        const float gf = gpre[r][jh][1] + acc[jh + 2][r];
        const float gg = gpre[r][jh][2] + acc[jh + 4][r];
        const float go = gpre[r][jh][3] + acc[jh + 6][r];
        const float cn = sig_(gf) * cc[jh][r] + sig_(gi) * tanh_(gg);
        const float hn = sig_(go) * tanh_(cn);
        cc[jh][r] = cn;
        const unsigned short hb = f2bf(hn);
        ht[b][jh * 16 + lr] = hb;
        if (seq_out) seq_out[(size_t)(s_idx * 32 + b) * 1024 + dir * 512 + jj] = hb;
      }
    }
    if (t < 63) fetch_g(t + 1);
    __syncthreads();  // ht complete
    {
      const int bb = tid >> 2, q = tid & 3;
      unsigned long long* HWU =
          (unsigned long long*)Hping + (((p ^ 1) * 2 + dir) * 32 + bb) * 128 + (j0 >> 2);
#pragma unroll
      for (int i = 0; i < 2; i++) {
        const int c = q * 2 + i;
        unsigned long long v = *(const unsigned long long*)&ht[bb][c * 4];
        coh_st(HWU + c, v);
      }
    }
    if (t < 63) grid_bar(cnt, flag, 16, sense);
  }
#pragma unroll
  for (int r = 0; r < 4; r++)
#pragma unroll
    for (int jh = 0; jh < 2; jh++)
      c_out[(dir * 32 + (w * 16 + kg * 4 + r)) * 512 + j0 + jh * 16 + lr] = cc[jh][r];
}

// ---------------------------------------------------------------------------
// Decoder chain: grid 64 (jtile16), block 128, 128KB dyn LDS.
// Hext rows (t+1)*32+b; rows 0..31 = init state. Coherent h exchange.
// ---------------------------------------------------------------------------
__global__ __launch_bounds__(128, 1) void dec_chain(
    const unsigned short* __restrict__ W, const unsigned short* __restrict__ G,
    const float* __restrict__ cinit, unsigned short* __restrict__ Hext,
    int* cnt, int* flag) {
  extern __shared__ unsigned short lw[];
  __shared__ unsigned short ht[32][20];  // 40B rows: pad for bank spread
  const int tid = threadIdx.x, lane = tid & 63, w = tid >> 6;
  const int lr = lane & 15, kg = lane >> 4;
  const int j0 = (int)blockIdx.x * 16, j = j0 + lr;
  for (int it = 0; it < 64; it++) {
    const int idx = (it * 128 + tid) * 16;
    const int r = idx >> 11, o = idx & 2047;
    const unsigned short* src = W + (size_t)((r >> 4) * 1024 + j0 + (r & 15)) * 1024 + (o >> 1);
    *(short8*)((char*)lw + r * 2048 + (o ^ ((r & 7) << 4))) = *(const short8*)src;
  }
  float cc[4];
#pragma unroll
  for (int r = 0; r < 4; r++) cc[r] = cinit[(w * 16 + kg * 4 + r) * 1024 + j];
  int sense = 0;
  float gpre[4][4];
  auto fetch_g = [&](int k) {
#pragma unroll
    for (int r = 0; r < 4; r++) {
      const unsigned short* Gr = G + (size_t)(k * 32 + (w * 16 + kg * 4 + r)) * 4096 + j;
      gpre[r][0] = bf2f(Gr[0]);
      gpre[r][1] = bf2f(Gr[1024]);
      gpre[r][2] = bf2f(Gr[2048]);
      gpre[r][3] = bf2f(Gr[3072]);
    }
  };
  fetch_g(0);
  __syncthreads();
  const unsigned long long* HU = (const unsigned long long*)Hext;
  for (int k = 0; k < 63; k++) {
    const int rowb = (k * 32 + w * 16 + lr) * 256 + kg * 2;
    short8 areg[32];
#pragma unroll
    for (int kc = 0; kc < 32; kc++)
      areg[kc] = mk8(coh_ld(HU + rowb + kc * 8), coh_ld(HU + rowb + kc * 8 + 1));
    f32x4 acc[4] = {};
#pragma unroll
    for (int kc = 0; kc < 32; kc++)
#pragma unroll
      for (int g = 0; g < 4; g++) {
        const int rr = g * 16 + lr;
        short8 bf = *(const short8*)((const char*)lw + rr * 2048 +
                                     ((kc * 64 + kg * 16) ^ ((rr & 7) << 4)));
        acc[g] = __builtin_amdgcn_mfma_f32_16x16x32_bf16(areg[kc], bf, acc[g], 0, 0, 0);
      }
#pragma unroll
    for (int r = 0; r < 4; r++) {
      const int b = w * 16 + kg * 4 + r;
      const float gi = gpre[r][0] + acc[0][r];
      const float gf = gpre[r][1] + acc[1][r];
      const float gg = gpre[r][2] + acc[2][r];
      const float go = gpre[r][3] + acc[3][r];
      const float cn = sig_(gf) * cc[r] + sig_(gi) * tanh_(gg);
      const float hn = sig_(go) * tanh_(cn);
      cc[r] = cn;
      ht[b][lr] = f2bf(hn);
    }
    if (k < 62) fetch_g(k + 1);
    __syncthreads();  // ht complete
    {
      const int bb = tid >> 2, q = tid & 3;
      unsigned long long v = *(const unsigned long long*)&ht[bb][q * 4];
      coh_st((unsigned long long*)Hext + ((size_t)(k + 1) * 32 + bb) * 256 + (j0 >> 2) + q, v);
    }
    if (k < 62) grid_bar(cnt, flag, 64, sense);
  }
}

// ---------------------------------------------------------------------------
// Setup kernels
// ---------------------------------------------------------------------------
__global__ void cvt_bf16(const float* __restrict__ in, unsigned short* __restrict__ out,
                         long n4) {
  long i = (long)blockIdx.x * blockDim.x + threadIdx.x;
  const long stride = (long)gridDim.x * blockDim.x;
  for (; i < n4; i += stride) {
    f32x4 v = *(const f32x4*)&in[i * 4];
    ushort4 o = {f2bf(v.x), f2bf(v.y), f2bf(v.z), f2bf(v.w)};
    *(ushort4*)&out[i * 4] = o;
  }
}

__global__ void bias_comb(const float* __restrict__ a, const float* __restrict__ b,
                          float* __restrict__ out, int n) {
  int i = blockIdx.x * blockDim.x + threadIdx.x;
  if (i < n) out[i] = a[i] + b[i];
}

__global__ void embed_src(const int* __restrict__ x, const float* __restrict__ emb,
                          unsigned short* __restrict__ A0) {
  const int row = blockIdx.x;
  const int s = row >> 5, b = row & 31;
  const int tok = x[b * 64 + (63 - s)];
  const int col = threadIdx.x * 4;
  f32x4 v = *(const f32x4*)(emb + (size_t)tok * 1024 + col);
  ushort4 o = {f2bf(v.x), f2bf(v.y), f2bf(v.z), f2bf(v.w)};
  *(ushort4*)&A0[(size_t)row * 1024 + col] = o;
}

__global__ void embed_tgt(const int* __restrict__ y, const float* __restrict__ emb,
                          unsigned short* __restrict__ inp0) {
  const int row = blockIdx.x;
  const int col = threadIdx.x * 4;
  ushort4 o = {0, 0, 0, 0};
  if (row < 2016) {
    const int t = row >> 5, b = row & 31;
    const int tok = y[b * 64 + t];
    f32x4 v = *(const f32x4*)(emb + (size_t)tok * 1024 + col);
    o = ushort4{f2bf(v.x), f2bf(v.y), f2bf(v.z), f2bf(v.w)};
  } else {
    *(ushort4*)&inp0[(size_t)row * 2048 + 1024 + col] = o;
  }
  *(ushort4*)&inp0[(size_t)row * 2048 + col] = o;
}

__global__ void fill_ctx2(const unsigned short* __restrict__ Hl1,
                          unsigned short* __restrict__ inp0) {
  const int row = blockIdx.x;
  const int b = row & 31;
  const int col = threadIdx.x * 4;
  const int dir = col >> 9, jj = col & 511;
  ushort4 v = *(const ushort4*)(Hl1 + ((size_t)dir * 32 + b) * 512 + jj);
  *(ushort4*)&inp0[(size_t)row * 2048 + 1024 + col] = v;
}

// init rows 0..31 of H0ext/H1ext + c bufs from encoder finals; grid 128 x 256
__global__ void dec_init2(const unsigned short* __restrict__ Hl0,
                          const unsigned short* __restrict__ Hl1,
                          const float* __restrict__ Cl0, const float* __restrict__ Cl1,
                          unsigned short* __restrict__ H0e, unsigned short* __restrict__ H1e,
                          float* __restrict__ c0, float* __restrict__ c1) {
  const int i = blockIdx.x * 256 + threadIdx.x;
  const int b = i >> 10, col = i & 1023;
  const int dir = col >> 9, jj = col & 511;
  const int se = (dir * 32 + b) * 512 + jj;
  const int de = b * 1024 + col;
  H0e[de] = Hl0[se];
  H1e[de] = Hl1[se];
  c0[de] = Cl0[se];
  c1[de] = Cl1[se];
}

// ---------------------------------------------------------------------------
extern "C" void kernel_launch(void* const* d_in, const int* in_sizes, int n_in,
                              void* d_out, int out_size, void* d_ws, size_t ws_size,
                              hipStream_t stream) {
  const int* x = (const int*)d_in[0];
  const int* y = (const int*)d_in[1];
  const float* src_emb = (const float*)d_in[2];
  const float* tgt_emb = (const float*)d_in[3];
  const float* enc_W_ih = (const float*)d_in[4];
  const float* enc_W_hh = (const float*)d_in[5];
  const float* enc_b_ih = (const float*)d_in[6];
  const float* enc_b_hh = (const float*)d_in[7];
  const float* dec_W_ih0 = (const float*)d_in[8];
  const float* dec_W_ih1 = (const float*)d_in[9];
  const float* dec_W_hh = (const float*)d_in[10];
  const float* dec_b_ih = (const float*)d_in[11];
  const float* dec_b_hh = (const float*)d_in[12];
  const float* W_out = (const float*)d_in[13];
  const float* b_out = (const float*)d_in[14];
  float* out = (float*)d_out;

  char* ws = (char*)d_ws;
  size_t off = 0;
  auto alloc = [&](size_t bytes) -> void* {
    void* p = ws + off;
    off += (bytes + 255) & ~(size_t)255;
    return p;
  };
  unsigned short* A0 = (unsigned short*)alloc(2048ull * 1024 * 2);
  unsigned short* seq1 = (unsigned short*)alloc(2048ull * 1024 * 2);
  unsigned short* Wih_bf = (unsigned short*)alloc(2ull * 4096 * 1024 * 2);
  unsigned short* Wih0_bf = (unsigned short*)alloc(4096ull * 2048 * 2);
  unsigned short* Wih1_bf = (unsigned short*)alloc(4096ull * 1024 * 2);
  unsigned short* Wout_bf = (unsigned short*)alloc(32000ull * 1024 * 2);
  unsigned short* G = (unsigned short*)alloc(2048ull * 4096 * 2);  // bf16 gates (reused)
  unsigned short* inp0 = (unsigned short*)alloc(2048ull * 2048 * 2);
  unsigned short* Whh_enc_bf = (unsigned short*)alloc(2ull * 2 * 2048 * 512 * 2);
  unsigned short* Whh0_bf = (unsigned short*)alloc(4096ull * 1024 * 2);
  unsigned short* Whh1_bf = (unsigned short*)alloc(4096ull * 1024 * 2);
  unsigned short* H0ext = (unsigned short*)alloc(2080ull * 1024 * 2);  // row0-31=init
  unsigned short* H1ext = (unsigned short*)alloc(2080ull * 1024 * 2);
  float* encbias = (float*)alloc(2ull * 4096 * 4);
  float* decdb = (float*)alloc(2ull * 4096 * 4);
  unsigned short* Hp_l0 = (unsigned short*)alloc(2ull * 2 * 32 * 512 * 2);  // [p][d][b][j]
  unsigned short* Hp_l1 = (unsigned short*)alloc(2ull * 2 * 32 * 512 * 2);
  float* c_l0 = (float*)alloc(2ull * 32 * 512 * 4);
  float* c_l1 = (float*)alloc(2ull * 32 * 512 * 4);
  float* c0buf = (float*)alloc(32ull * 1024 * 4);
  float* c1buf = (float*)alloc(32ull * 1024 * 4);
  int* bar = (int*)alloc(256 * 4);  // barrier pairs, reset every call
  if (off > ws_size) return;

  hipFuncSetAttribute((const void*)enc_chain,
                      hipFuncAttributeMaxDynamicSharedMemorySize, 131072);
  hipFuncSetAttribute((const void*)dec_chain,
                      hipFuncAttributeMaxDynamicSharedMemorySize, 131072);

  // ---- setup ----
  cvt_bf16<<<1024, 256, 0, stream>>>(enc_W_ih, Wih_bf, (2ll * 4096 * 1024) / 4);
  cvt_bf16<<<1024, 256, 0, stream>>>(dec_W_ih0, Wih0_bf, (4096ll * 2048) / 4);
  cvt_bf16<<<1024, 256, 0, stream>>>(dec_W_ih1, Wih1_bf, (4096ll * 1024) / 4);
  cvt_bf16<<<2048, 256, 0, stream>>>(W_out, Wout_bf, (32000ll * 1024) / 4);
  cvt_bf16<<<1024, 256, 0, stream>>>(enc_W_hh, Whh_enc_bf, (2ll * 2 * 2048 * 512) / 4);
  cvt_bf16<<<1024, 256, 0, stream>>>(dec_W_hh, Whh0_bf, (4096ll * 1024) / 4);
  cvt_bf16<<<1024, 256, 0, stream>>>(dec_W_hh + 4096ll * 1024, Whh1_bf, (4096ll * 1024) / 4);
  bias_comb<<<32, 256, 0, stream>>>(enc_b_ih, enc_b_hh, encbias, 8192);
  bias_comb<<<32, 256, 0, stream>>>(dec_b_ih, dec_b_hh, decdb, 8192);
  embed_src<<<2048, 256, 0, stream>>>(x, src_emb, A0);
  embed_tgt<<<2048, 256, 0, stream>>>(y, tgt_emb, inp0);
  hipMemsetAsync(Hp_l0, 0, 2ull * (2 * 2 * 32 * 512) * 2, stream);  // Hp_l0 + Hp_l1
  hipMemsetAsync(bar, 0, 256 * 4, stream);  // replay-safe barrier reset

  // ---- encoder layer 0 ----
  gemm_bf16<<<dim3(32, 16), 256, 0, stream>>>(A0, Wih_bf, G, encbias, 1024, 4096, 2048, 2);
  enc_chain<<<32, 128, 131072, stream>>>(Whh_enc_bf, G, Hp_l0, seq1, c_l0, bar + 0);
  // ---- encoder layer 1 ----
  gemm_bf16<<<dim3(32, 16), 256, 0, stream>>>(seq1, Wih_bf + 4096ull * 1024, G,
                                              encbias + 4096, 1024, 4096, 2048, 2);
  enc_chain<<<32, 128, 131072, stream>>>(Whh_enc_bf + 2ull * 2048 * 512, G, Hp_l1, nullptr,
                                         c_l1, bar + 64);

  // ---- decoder setup ----
  dec_init2<<<128, 256, 0, stream>>>(Hp_l0, Hp_l1, c_l0, c_l1, H0ext, H1ext, c0buf, c1buf);
  fill_ctx2<<<2016, 256, 0, stream>>>(Hp_l1, inp0);
  gemm_bf16<<<dim3(32, 16), 256, 0, stream>>>(inp0, Wih0_bf, G, decdb, 2048, 4096, 2048, 2);

  // ---- decoder cell0 chain ----
  dec_chain<<<64, 128, 131072, stream>>>(Whh0_bf, G, c0buf, H0ext, bar + 128, bar + 144);
  // ---- G1 = H0seq @ Wih1^T + db1 ----
  gemm_bf16<<<dim3(32, 16), 256, 0, stream>>>(H0ext + 32ull * 1024, Wih1_bf, G,
                                              decdb + 4096, 1024, 4096, 2016, 2);
  // ---- decoder cell1 chain ----
  dec_chain<<<64, 128, 131072, stream>>>(Whh1_bf, G, c1buf, H1ext, bar + 160, bar + 176);

  // ---- logits ----
  gemm_bf16<<<dim3(250, 16), 256, 0, stream>>>(H1ext + 32ull * 1024, Wout_bf, out, b_out,
                                               1024, 32000, 2016, 1);
}